// Round 9
// baseline (468.717 us; speedup 1.0000x reference)
//
#include <hip/hip_runtime.h>
#include <hip/hip_bf16.h>

// Problem constants
#define BSZ 16
#define LP 128
#define LR 1024
#define DD 128
#define DG 640
#define KH 7
#define SPLITK 4

typedef __bf16 bf16x8 __attribute__((ext_vector_type(8)));
typedef __bf16 bf16x4v __attribute__((ext_vector_type(4)));
typedef float f32x4 __attribute__((ext_vector_type(4)));
typedef unsigned int uint32;

// ---------------------------------------------------------------------------
// MFMA core, bf16 A and B: 128(M) x 64(N) tile, BK=32, 4 waves (each 32x64),
// depth-1 prefetch (r6-proven schedule). LDS = 15.4KB -> 8 blocks/CU
// (full 32-wave residency; VGPR 56 permits 8 waves/SIMD). One 16x16x32
// MFMA per (fi,fj) per iter; per-thread staging = 3 int4 (A:2, B:1).
// Pad 40 ushorts (80B stride, 20-bank stagger -> max 2-way = free).
// ---------------------------------------------------------------------------
__device__ __forceinline__ void mfma_core_n64(
    const ushort* __restrict__ Ab, int lda,
    const ushort* __restrict__ Bb, int ldb,
    int m0, int n0, int kStart, int kEnd, f32x4 (&acc)[2][4]) {
  __shared__ __align__(16) ushort As[128 * 40];
  __shared__ __align__(16) ushort Bs[64 * 40];
  int t = threadIdx.x;
  int wave = t >> 6, lane = t & 63;
  int quad = lane >> 4, l16 = lane & 15;
  int wm = wave * 32;
  int ra = t >> 1, oa = (t & 1) * 16;   // A: 128 rows x 2 half-rows (2 int4)
  int rb = t >> 2, ob = (t & 3) * 8;    // B: 64 rows x 4 chunks (1 int4)

  int4 a0, a1, b0;
  auto load_k = [&](int k0) {
    a0 = *(const int4*)(Ab + (size_t)(m0 + ra) * lda + k0 + oa);
    a1 = *(const int4*)(Ab + (size_t)(m0 + ra) * lda + k0 + oa + 8);
    b0 = *(const int4*)(Bb + (size_t)(n0 + rb) * ldb + k0 + ob);
  };

  load_k(kStart);
  for (int k0 = kStart; k0 < kEnd; k0 += 32) {
    __syncthreads();   // previous iteration's LDS fully consumed
    *(int4*)&As[ra * 40 + oa] = a0;
    *(int4*)&As[ra * 40 + oa + 8] = a1;
    *(int4*)&Bs[rb * 40 + ob] = b0;
    __syncthreads();
    if (k0 + 32 < kEnd) load_k(k0 + 32);  // prefetch under compute
    bf16x8 af[2], bfr[4];
    #pragma unroll
    for (int fi = 0; fi < 2; ++fi)
      af[fi] = *(const bf16x8*)&As[(wm + fi * 16 + l16) * 40 + quad * 8];
    #pragma unroll
    for (int fj = 0; fj < 4; ++fj)
      bfr[fj] = *(const bf16x8*)&Bs[(fj * 16 + l16) * 40 + quad * 8];
    #pragma unroll
    for (int fi = 0; fi < 2; ++fi)
      #pragma unroll
      for (int fj = 0; fj < 4; ++fj)
        acc[fi][fj] = __builtin_amdgcn_mfma_f32_16x16x32_bf16(
            af[fi], bfr[fj], acc[fi][fj], 0, 0, 0);
  }
}

// ---------------------------------------------------------------------------
// agg core: A built in-register from packed adjacency bits, 128(M)x64(N),
// BK=32, depth-1 prefetch. LDS = 5.6KB (wave-capped 8 blocks/CU).
// acc[c][d] += sum_r Ahat[r,c] * Xt[d][bcol + r]
// ---------------------------------------------------------------------------
__device__ __forceinline__ void agg_core_n64(
    const uint32* __restrict__ pb, int L,
    const ushort* __restrict__ Bb, int ldb,
    int m0, int n0, f32x4 (&acc)[2][4]) {
  __shared__ __align__(16) ushort Bs[64 * 40];
  __shared__ uint32 Aw[128];
  int t = threadIdx.x;
  int wave = t >> 6, lane = t & 63;
  int quad = lane >> 4, l16 = lane & 15;
  int wm = wave * 32;
  int rb = t >> 2, ob = (t & 3) * 8;

  int4 b0;
  uint32 w = 0;
  auto load_k = [&](int k0) {
    b0 = *(const int4*)(Bb + (size_t)(n0 + rb) * ldb + k0 + ob);
    if (t < 128) w = pb[(size_t)(k0 >> 5) * L + m0 + t];
  };

  load_k(0);
  for (int k0 = 0; k0 < L; k0 += 32) {
    __syncthreads();
    *(int4*)&Bs[rb * 40 + ob] = b0;
    if (t < 128) Aw[t] = w;
    __syncthreads();
    if (k0 + 32 < L) load_k(k0 + 32);  // prefetch under compute
    bf16x8 af[2], bfr[4];
    #pragma unroll
    for (int fj = 0; fj < 4; ++fj)
      bfr[fj] = *(const bf16x8*)&Bs[(fj * 16 + l16) * 40 + quad * 8];
    #pragma unroll
    for (int fi = 0; fi < 2; ++fi) {
      uint32 bits = (Aw[wm + fi * 16 + l16] >> (quad * 8)) & 0xffu;
      int4 p;
      p.x = (int)((((bits >> 0) & 1) ? 0x3F80u : 0u) | (((bits >> 1) & 1) ? 0x3F800000u : 0u));
      p.y = (int)((((bits >> 2) & 1) ? 0x3F80u : 0u) | (((bits >> 3) & 1) ? 0x3F800000u : 0u));
      p.z = (int)((((bits >> 4) & 1) ? 0x3F80u : 0u) | (((bits >> 5) & 1) ? 0x3F800000u : 0u));
      p.w = (int)((((bits >> 6) & 1) ? 0x3F80u : 0u) | (((bits >> 7) & 1) ? 0x3F800000u : 0u));
      af[fi] = *(bf16x8*)&p;
    }
    #pragma unroll
    for (int fi = 0; fi < 2; ++fi)
      #pragma unroll
      for (int fj = 0; fj < 4; ++fj)
        acc[fi][fj] = __builtin_amdgcn_mfma_f32_16x16x32_bf16(
            af[fi], bfr[fj], acc[fi][fj], 0, 0, 0);
  }
}

// ---------------------------------------------------------------------------
// MFMA core, f32 A (converted to bf16 during staging), 64(M)x128(N), BK=64,
// depth-1 prefetch. Used only by pre_gemm (r8 verbatim).
// ---------------------------------------------------------------------------
__device__ __forceinline__ void mfma_core_f32_m64(
    const float* __restrict__ Af, int lda,
    const ushort* __restrict__ Bb, int ldb,
    int m0, int kStart, int kEnd, f32x4 (&acc)[2][4]) {
  __shared__ __align__(16) ushort As[64 * 72];
  __shared__ __align__(16) ushort Bs[128 * 72];
  int t = threadIdx.x;
  int wave = t >> 6, lane = t & 63;
  int quad = lane >> 4, l16 = lane & 15;
  int wm = (wave >> 1) * 32, wn = (wave & 1) * 64;
  int r1 = t >> 2, o1 = (t & 3) * 16;

  int4 b00, b01, b10, b11;
  float4 af32[4];

  auto load_k = [&](int k0) {
    b00 = *(const int4*)(Bb + (size_t)r1 * ldb + k0 + o1);
    b01 = *(const int4*)(Bb + (size_t)r1 * ldb + k0 + o1 + 8);
    b10 = *(const int4*)(Bb + (size_t)(r1 + 64) * ldb + k0 + o1);
    b11 = *(const int4*)(Bb + (size_t)(r1 + 64) * ldb + k0 + o1 + 8);
    #pragma unroll
    for (int s = 0; s < 4; ++s) {
      int idx = t + s * 256;
      int row = idx >> 4, c4 = (idx & 15) * 4;
      af32[s] = *(const float4*)(Af + (size_t)(m0 + row) * lda + k0 + c4);
    }
  };

  load_k(kStart);
  for (int k0 = kStart; k0 < kEnd; k0 += 64) {
    __syncthreads();
    #pragma unroll
    for (int s = 0; s < 4; ++s) {
      int idx = t + s * 256;
      int row = idx >> 4, c4 = (idx & 15) * 4;
      ushort4 u; __bf16 h;
      h = (__bf16)af32[s].x; u.x = *(ushort*)&h;
      h = (__bf16)af32[s].y; u.y = *(ushort*)&h;
      h = (__bf16)af32[s].z; u.z = *(ushort*)&h;
      h = (__bf16)af32[s].w; u.w = *(ushort*)&h;
      *(ushort4*)&As[row * 72 + c4] = u;
    }
    *(int4*)&Bs[r1 * 72 + o1] = b00;
    *(int4*)&Bs[r1 * 72 + o1 + 8] = b01;
    *(int4*)&Bs[(r1 + 64) * 72 + o1] = b10;
    *(int4*)&Bs[(r1 + 64) * 72 + o1 + 8] = b11;
    __syncthreads();
    if (k0 + 64 < kEnd) load_k(k0 + 64);  // prefetch under compute
    #pragma unroll
    for (int kc = 0; kc < 2; ++kc) {
      bf16x8 af[2], bfr[4];
      #pragma unroll
      for (int fi = 0; fi < 2; ++fi)
        af[fi] = *(const bf16x8*)&As[(wm + fi * 16 + l16) * 72 + kc * 32 + quad * 8];
      #pragma unroll
      for (int fj = 0; fj < 4; ++fj)
        bfr[fj] = *(const bf16x8*)&Bs[(wn + fj * 16 + l16) * 72 + kc * 32 + quad * 8];
      #pragma unroll
      for (int fi = 0; fi < 2; ++fi)
        #pragma unroll
        for (int fj = 0; fj < 4; ++fj)
          acc[fi][fj] = __builtin_amdgcn_mfma_f32_16x16x32_bf16(
              af[fi], bfr[fj], acc[fi][fj], 0, 0, 0);
    }
  }
}

// ---------------------------------------------------------------------------
// prep_all: weight conversions/transposes AND adjacency packing in ONE 1D
// dispatch. Block ranges:
//   [0,256)      WppT transposes  (2 x 128 tiles of 1024x128)
//   [256,1856)   Wg transposes    (4 x 400 tiles of 640x640)
//   [1856,2976)  WtB f32->bf16    (2 x 560 chunks)
//   [2976,5024)  pro pack, [5024,5088) pep pack
// ---------------------------------------------------------------------------
__device__ __forceinline__ void tr_tile(const float* __restrict__ src,
                                        __bf16* __restrict__ dst,
                                        int R, int C, int cb, int rb, int t) {
  __shared__ float T[32][33];
  int r0 = rb * 32, c0 = cb * 32;
  #pragma unroll
  for (int s = 0; s < 4; ++s) {
    int idx = t + s * 256;
    int r = idx >> 5, c = idx & 31;
    T[r][c] = src[(size_t)(r0 + r) * C + c0 + c];
  }
  __syncthreads();
  #pragma unroll
  for (int s = 0; s < 4; ++s) {
    int idx = t + s * 256;
    int c = idx >> 5, r = idx & 31;
    dst[(size_t)(c0 + c) * R + r0 + r] = (__bf16)T[r][c];
  }
}

__device__ __forceinline__ void pack_col(const float* __restrict__ adjB,
                                         uint32* __restrict__ packed,
                                         int L, int b, int rw, int c) {
  uint32 w = 0;
  int rbase = rw * 32;
  #pragma unroll 8
  for (int j = 0; j < 32; ++j) {
    float a = adjB[(size_t)(rbase + j) * L + c];
    if (a != 0.f || (rbase + j) == c) w |= (1u << j);
  }
  packed[((size_t)b * (L >> 5) + rw) * L + c] = w;
}

__global__ __launch_bounds__(256) void prep_all(
    const float* __restrict__ Wppep, const float* __restrict__ Wppro,
    const float* __restrict__ Wg1p, const float* __restrict__ Wg2p,
    const float* __restrict__ Wg1r, const float* __restrict__ Wg2r,
    const float* __restrict__ Wtp, const float* __restrict__ Wtr,
    const float* __restrict__ adjP, const float* __restrict__ adjR,
    __bf16* __restrict__ WppTp, __bf16* __restrict__ WppTr,
    __bf16* __restrict__ Wg1Tp, __bf16* __restrict__ Wg2Tp,
    __bf16* __restrict__ Wg1Tr, __bf16* __restrict__ Wg2Tr,
    __bf16* __restrict__ WtBp, __bf16* __restrict__ WtBr,
    uint32* __restrict__ packedP, uint32* __restrict__ packedR) {
  int g = blockIdx.x, t = threadIdx.x;
  if (g < 256) {
    int zi = g >> 7, bx = g & 127;
    tr_tile(zi ? Wppro : Wppep, zi ? WppTr : WppTp, 1024, 128, bx % 4, bx / 4, t);
  } else if (g < 1856) {
    int u = g - 256;
    int zi = u / 400, bx = u % 400;
    const float* src = (zi == 0) ? Wg1p : (zi == 1) ? Wg2p : (zi == 2) ? Wg1r : Wg2r;
    __bf16* dst = (zi == 0) ? Wg1Tp : (zi == 1) ? Wg2Tp : (zi == 2) ? Wg1Tr : Wg2Tr;
    tr_tile(src, dst, 640, 640, bx % 20, bx / 20, t);
  } else if (g < 2976) {
    int u = g - 1856;
    int zi = u / 560, bx = u % 560;
    const float* src = zi ? Wtr : Wtp;
    __bf16* dst = zi ? WtBr : WtBp;
    int i = bx * 256 + t;  // < 143360 float4s
    float4 v = ((const float4*)src)[i];
    bf16x4v o;
    o.x = (__bf16)v.x; o.y = (__bf16)v.y; o.z = (__bf16)v.z; o.w = (__bf16)v.w;
    ((bf16x4v*)dst)[i] = o;
  } else if (g < 5024) {
    int u = g - 2976;
    int b = u >> 7, rem = u & 127;
    int rw = rem >> 2, c = (rem & 3) * 256 + t;
    pack_col(adjR + (size_t)b * LR * LR, packedR, LR, b, rw, c);
  } else {
    int u = g - 5024;
    if (t >= LP) return;
    pack_col(adjP + (size_t)(u >> 2) * LP * LP, packedP, LP, u >> 2, u & 3, t);
  }
}

// ---------------------------------------------------------------------------
// pre_gemm merged (split-K pretrain partials): grid (288, SPLITK).
// bx<32: pep m-block bx (64 rows each); else pro m-block bx-32. by = k-slice.
// ---------------------------------------------------------------------------
__global__ __launch_bounds__(256) void pre_gemm(
    const float* __restrict__ XpP, const float* __restrict__ XpR,
    const __bf16* __restrict__ WppTp, const __bf16* __restrict__ WppTr,
    float* __restrict__ partP, float* __restrict__ partR) {
  int bx = blockIdx.x, s = blockIdx.y;
  int pep = bx < (BSZ * LP / 64);
  int m0 = (pep ? bx : bx - BSZ * LP / 64) * 64;
  const float* A = pep ? XpP : XpR;
  const ushort* B = (const ushort*)(pep ? WppTp : WppTr);
  int BL = pep ? BSZ * LP : BSZ * LR;
  float* part = (pep ? partP : partR) + (size_t)s * BL * DD;

  f32x4 acc[2][4];
  #pragma unroll
  for (int i = 0; i < 2; ++i)
    #pragma unroll
    for (int j = 0; j < 4; ++j) acc[i][j] = (f32x4){0.f, 0.f, 0.f, 0.f};
  mfma_core_f32_m64(A, 1024, B, 1024, m0, s * (1024 / SPLITK),
                    (s + 1) * (1024 / SPLITK), acc);

  int t = threadIdx.x;
  int wave = t >> 6, lane = t & 63;
  int quad = lane >> 4, l16 = lane & 15;
  int wm = (wave >> 1) * 32, wn = (wave & 1) * 64;
  #pragma unroll
  for (int fi = 0; fi < 2; ++fi)
    #pragma unroll
    for (int r = 0; r < 4; ++r) {
      int m = m0 + wm + fi * 16 + quad * 4 + r;
      #pragma unroll
      for (int fj = 0; fj < 4; ++fj) {
        int n = wn + fj * 16 + l16;
        part[(size_t)m * DD + n] = acc[fi][fj][r];
      }
    }
}

// ---------------------------------------------------------------------------
// Encoder merged: embeddings + dense matmul + pretrain-partial reduce
// + dinv from packed-bit popcount. grid (BLp + BLr, 128 threads)
// ---------------------------------------------------------------------------
__global__ __launch_bounds__(128) void encoder_merged(
    const int* __restrict__ xsP, const int* __restrict__ xssP,
    const int* __restrict__ x2P, const float* __restrict__ xdP,
    const float* __restrict__ WdP, const float* __restrict__ bdP,
    const float* __restrict__ maskP, const float* __restrict__ partP,
    const float* __restrict__ bppP, __bf16* __restrict__ encP,
    const uint32* __restrict__ packedP, float* __restrict__ dinvP,
    const int* __restrict__ xsR, const int* __restrict__ xssR,
    const int* __restrict__ x2R, const float* __restrict__ xdR,
    const float* __restrict__ WdR, const float* __restrict__ bdR,
    const float* __restrict__ maskR, const float* __restrict__ partR,
    const float* __restrict__ bppR, __bf16* __restrict__ encR,
    const uint32* __restrict__ packedR, float* __restrict__ dinvR,
    const float* __restrict__ Eseq, const float* __restrict__ Ess,
    const float* __restrict__ Etwo) {
  int gw = blockIdx.x;
  int t = threadIdx.x;
  int pep = gw < BSZ * LP;
  int row = pep ? gw : gw - BSZ * LP;
  int L = pep ? LP : LR;
  int BL = pep ? BSZ * LP : BSZ * LR;
  int Kd = pep ? 3 : 23;
  const int* xs = pep ? xsP : xsR;
  const int* xss = pep ? xssP : xssR;
  const int* x2 = pep ? x2P : x2R;
  const float* xd = pep ? xdP : xdR;
  const float* Wd = pep ? WdP : WdR;
  const float* bd = pep ? bdP : bdR;
  const float* mask = pep ? maskP : maskR;
  const float* part = pep ? partP : partR;
  const float* bpp = pep ? bppP : bppR;
  const uint32* packed = pep ? packedP : packedR;
  float* dinv = pep ? dinvP : dinvR;
  __bf16* enc = pep ? encP : encR;

  // dinv from packed popcount: wave 0, lanes 0..nw-1 (nw = L/32)
  int nw = L >> 5;
  int bb = row / L, ccol = row % L;
  uint32 wv = (t < nw) ? packed[((size_t)bb * nw + t) * L + ccol] : 0u;
  int cnt = __popc(wv);
  if (t < 64) {
    #pragma unroll
    for (int off = 16; off >= 1; off >>= 1) cnt += __shfl_down(cnt, off);
    if (t == 0) dinv[row] = rsqrtf((float)cnt);
  }

  float m = mask[row];
  int i0 = xs[row], i1 = xss[row], i2 = x2[row];
  __bf16* e = enc + (size_t)row * DG;
  e[t]        = (__bf16)(Eseq[i0 * DD + t] * m);
  e[DD + t]   = (__bf16)(Ess[i1 * DD + t] * m);
  e[2*DD + t] = (__bf16)(Etwo[i2 * DD + t] * m);
  float acc = bd[t];
  const float* xr = xd + (size_t)row * Kd;
  for (int i = 0; i < Kd; ++i) acc = fmaf(xr[i], Wd[i * DD + t], acc);
  e[3*DD + t] = (__bf16)(acc * m);
  // pretrain reduce -> cols 512..639
  float p = bpp[t];
  #pragma unroll
  for (int s = 0; s < SPLITK; ++s)
    p += part[(size_t)s * BL * DD + (size_t)row * DD + t];
  e[4*DD + t] = (__bf16)(p * m);
}

// ---------------------------------------------------------------------------
// linT merged: bufAT[d][row] = dinv[row] * sum_k src[row][k] * Wg[k][d]
// grid (288, 5): bx<32 pep n-block (64 rows each), else pro. by = m-block (d).
// ---------------------------------------------------------------------------
__global__ __launch_bounds__(256) void linT_merged(
    const __bf16* __restrict__ WgTp, const __bf16* __restrict__ srcP,
    const float* __restrict__ dinvP, __bf16* __restrict__ dstP,
    const __bf16* __restrict__ WgTr, const __bf16* __restrict__ srcR,
    const float* __restrict__ dinvR, __bf16* __restrict__ dstR) {
  int bx = blockIdx.x;
  int pep = bx < (BSZ * LP / 64);
  int n0 = (pep ? bx : bx - BSZ * LP / 64) * 64;
  int m0 = blockIdx.y * 128;
  int BL = pep ? BSZ * LP : BSZ * LR;
  const ushort* A = (const ushort*)(pep ? WgTp : WgTr);
  const ushort* B = (const ushort*)(pep ? srcP : srcR);
  const float* dinv = pep ? dinvP : dinvR;
  __bf16* dst = pep ? dstP : dstR;

  f32x4 acc[2][4];
  #pragma unroll
  for (int i = 0; i < 2; ++i)
    #pragma unroll
    for (int j = 0; j < 4; ++j) acc[i][j] = (f32x4){0.f, 0.f, 0.f, 0.f};
  mfma_core_n64(A, DG, B, DG, m0, n0, 0, DG, acc);

  int t = threadIdx.x;
  int wave = t >> 6, lane = t & 63;
  int quad = lane >> 4, l16 = lane & 15;
  int wm = wave * 32;
  #pragma unroll
  for (int fi = 0; fi < 2; ++fi)
    #pragma unroll
    for (int r = 0; r < 4; ++r) {
      int m = m0 + wm + fi * 16 + quad * 4 + r;
      #pragma unroll
      for (int fj = 0; fj < 4; ++fj) {
        int n = n0 + fj * 16 + l16;
        dst[(size_t)m * BL + n] = (__bf16)(acc[fi][fj][r] * dinv[n]);
      }
    }
}

// ---------------------------------------------------------------------------
// agg merged, XCD-aware grid: (160, 9).
// bx encodes (b = bx/10, n0 = (bx%10)*64). by==0: pep (m0=0); else pro
// m-block by-1. Y[b,c,d] = relu(dinv*acc + bias[d] (+encE)) * (mask?)
// ---------------------------------------------------------------------------
__global__ __launch_bounds__(256) void agg_merged(
    const uint32* __restrict__ packedP, const __bf16* __restrict__ XtP,
    const float* __restrict__ dinvP, const float* __restrict__ biasP,
    const __bf16* __restrict__ encEP, const float* __restrict__ maskP,
    __bf16* __restrict__ YP,
    const uint32* __restrict__ packedR, const __bf16* __restrict__ XtR,
    const float* __restrict__ dinvR, const float* __restrict__ biasR,
    const __bf16* __restrict__ encER, const float* __restrict__ maskR,
    __bf16* __restrict__ YR) {
  int bx = blockIdx.x;
  int b = bx / 10;
  int n0 = (bx % 10) * 64;
  int pep = (blockIdx.y == 0);
  int L = pep ? LP : LR;
  int BL = BSZ * L;
  int m0 = pep ? 0 : (blockIdx.y - 1) * 128;
  const uint32* pb = (pep ? packedP : packedR) + (size_t)b * (L >> 5) * L;
  const ushort* Bb = (const ushort*)(pep ? XtP : XtR) + (size_t)b * L;
  const float* dinv = pep ? dinvP : dinvR;
  const float* bias = pep ? biasP : biasR;
  const __bf16* encE = pep ? encEP : encER;
  const float* mask = pep ? maskP : maskR;
  __bf16* Y = pep ? YP : YR;

  f32x4 acc[2][4];
  #pragma unroll
  for (int i = 0; i < 2; ++i)
    #pragma unroll
    for (int j = 0; j < 4; ++j) acc[i][j] = (f32x4){0.f, 0.f, 0.f, 0.f};
  agg_core_n64(pb, L, Bb, BL, m0, n0, acc);

  int t = threadIdx.x;
  int wave = t >> 6, lane = t & 63;
  int quad = lane >> 4, l16 = lane & 15;
  int wm = wave * 32;
  int gRow = b * L;
  #pragma unroll
  for (int fi = 0; fi < 2; ++fi)
    #pragma unroll
    for (int r = 0; r < 4; ++r) {
      int m = m0 + wm + fi * 16 + quad * 4 + r;
      int gi = gRow + m;
      float di = dinv[gi];
      float rm = mask ? mask[gi] : 1.f;
      #pragma unroll
      for (int fj = 0; fj < 4; ++fj) {
        int n = n0 + fj * 16 + l16;
        float v = acc[fi][fj][r] * di + bias[n];
        if (encE) v += (float)encE[(size_t)gi * DG + n];
        v = fmaxf(v, 0.f);
        v *= rm;
        Y[(size_t)gi * DG + n] = (__bf16)v;
      }
    }
}

// ---------------------------------------------------------------------------
// fct merged: grid (16, 7, 18). bz<16: pro (b=bz, n0=bx*64 over LR);
// bz>=16: pep (chunk=(bz-16)*16+bx over BLp flattened). out f32.
// ---------------------------------------------------------------------------
__global__ __launch_bounds__(256) void fct_merged(
    const __bf16* __restrict__ WtBp, const float* __restrict__ btp,
    const __bf16* __restrict__ Yp, float* __restrict__ outP,
    const __bf16* __restrict__ WtBr, const float* __restrict__ btr,
    const __bf16* __restrict__ Yr, float* __restrict__ outR) {
  int kh = blockIdx.y;
  int pro = (blockIdx.z < 16);
  const ushort* A;
  const ushort* B;
  const float* bt;
  int n0;
  if (pro) {
    A = (const ushort*)(WtBr + (size_t)kh * DD * DG);
    B = (const ushort*)(Yr + (size_t)blockIdx.z * LR * DG);
    bt = btr;
    n0 = blockIdx.x * 64;
  } else {
    A = (const ushort*)(WtBp + (size_t)kh * DD * DG);
    B = (const ushort*)Yp;
    bt = btp;
    n0 = ((blockIdx.z - 16) * 16 + blockIdx.x) * 64;
  }

  f32x4 acc[2][4];
  #pragma unroll
  for (int i = 0; i < 2; ++i)
    #pragma unroll
    for (int j = 0; j < 4; ++j) acc[i][j] = (f32x4){0.f, 0.f, 0.f, 0.f};
  mfma_core_n64(A, DG, B, DG, 0, n0, 0, DG, acc);

  int t = threadIdx.x;
  int wave = t >> 6, lane = t & 63;
  int quad = lane >> 4, l16 = lane & 15;
  int wm = wave * 32;
  #pragma unroll
  for (int fi = 0; fi < 2; ++fi)
    #pragma unroll
    for (int r = 0; r < 4; ++r) {
      int m = wm + fi * 16 + quad * 4 + r;
      float bb = bt[kh * DD + m];
      #pragma unroll
      for (int fj = 0; fj < 4; ++fj) {
        int n = n0 + fj * 16 + l16;
        float v = fmaxf(acc[fi][fj][r] + bb, 0.f);
        if (pro) {
          outR[((size_t)(kh * BSZ + blockIdx.z) * DD + m) * LR + n] = v;
        } else {
          int b = n >> 7, l = n & 127;
          outP[((size_t)(kh * BSZ + b) * DD + m) * LP + l] = v;
        }
      }
    }
}

// ---------------------------------------------------------------------------
extern "C" void kernel_launch(void* const* d_in, const int* in_sizes, int n_in,
                              void* d_out, int out_size, void* d_ws, size_t ws_size,
                              hipStream_t stream) {
  const int*   x_pep          = (const int*)d_in[0];
  const int*   x_ss_pep       = (const int*)d_in[1];
  const int*   x_2_pep        = (const int*)d_in[2];
  const float* x_dense_pep    = (const float*)d_in[3];
  const float* x_pretrain_pep = (const float*)d_in[4];
  const int*   x_pro          = (const int*)d_in[5];
  const int*   x_ss_pro       = (const int*)d_in[6];
  const int*   x_2_pro        = (const int*)d_in[7];
  const float* x_dense_pro    = (const float*)d_in[8];
  const float* x_pretrain_pro = (const float*)d_in[9];
  const float* x_edge_pep     = (const float*)d_in[10];
  const float* x_edge_pro     = (const float*)d_in[11];
  const float* mask_pep       = (const float*)d_in[12];
  const float* mask_pro       = (const float*)d_in[13];
  const float* E_seq          = (const float*)d_in[14];
  const float* E_ss           = (const float*)d_in[15];
  const float* E_two          = (const float*)d_in[16];
  const float* W_dpep         = (const float*)d_in[17];
  const float* b_dpep         = (const float*)d_in[18];
  const float* W_dpro         = (const float*)d_in[19];
  const float* b_dpro         = (const float*)d_in[20];
  const float* W_ppep         = (const float*)d_in[21];
  const float* b_ppep         = (const float*)d_in[22];
  const float* W_ppro         = (const float*)d_in[23];
  const float* b_ppro         = (const float*)d_in[24];
  const float* Wg_pep1        = (const float*)d_in[25];
  const float* bg_pep1        = (const float*)d_in[26];
  const float* Wg_pep2        = (const float*)d_in[27];
  const float* bg_pep2        = (const float*)d_in[28];
  const float* Wg_pro1        = (const float*)d_in[29];
  const float* bg_pro1        = (const float*)d_in[30];
  const float* Wg_pro2        = (const float*)d_in[31];
  const float* bg_pro2        = (const float*)d_in[32];
  const float* Wt_pep         = (const float*)d_in[33];
  const float* bt_pep         = (const float*)d_in[34];
  const float* Wt_pro         = (const float*)d_in[35];
  const float* bt_pro         = (const float*)d_in[36];

  float* out = (float*)d_out;
  const int BLp = BSZ * LP;   // 2048
  const int BLr = BSZ * LR;   // 16384
  const size_t out_pro_off = (size_t)KH * BSZ * DD * LP;

  // Workspace layout (~117 MB)
  char* w = (char*)d_ws;
  __bf16* encBp  = (__bf16*)w; w += (size_t)BLp * DG * 2;
  __bf16* encBr  = (__bf16*)w; w += (size_t)BLr * DG * 2;
  __bf16* bufATp = (__bf16*)w; w += (size_t)DG * BLp * 2;
  __bf16* bufATr = (__bf16*)w; w += (size_t)DG * BLr * 2;
  __bf16* bufYp  = (__bf16*)w; w += (size_t)BLp * DG * 2;
  __bf16* bufYr  = (__bf16*)w; w += (size_t)BLr * DG * 2;
  __bf16* WppTp  = (__bf16*)w; w += (size_t)DD * 1024 * 2;
  __bf16* WppTr  = (__bf16*)w; w += (size_t)DD * 1024 * 2;
  __bf16* Wg1Tp  = (__bf16*)w; w += (size_t)DG * DG * 2;
  __bf16* Wg2Tp  = (__bf16*)w; w += (size_t)DG * DG * 2;
  __bf16* Wg1Tr  = (__bf16*)w; w += (size_t)DG * DG * 2;
  __bf16* Wg2Tr  = (__bf16*)w; w += (size_t)DG * DG * 2;
  __bf16* WtBp   = (__bf16*)w; w += (size_t)KH * DD * DG * 2;
  __bf16* WtBr   = (__bf16*)w; w += (size_t)KH * DD * DG * 2;
  uint32* packedP = (uint32*)w; w += (size_t)BSZ * (LP / 32) * LP * 4;
  uint32* packedR = (uint32*)w; w += (size_t)BSZ * (LR / 32) * LR * 4;
  float* dinvP = (float*)w; w += (size_t)BLp * 4;
  float* dinvR = (float*)w; w += (size_t)BLr * 4;
  float* partP = (float*)w; w += (size_t)SPLITK * BLp * DD * 4;
  float* partR = (float*)w; w += (size_t)SPLITK * BLr * DD * 4;

  // 1. weights + adjacency pack (single merged dispatch, no atomics)
  prep_all<<<5088, 256, 0, stream>>>(
      W_ppep, W_ppro, Wg_pep1, Wg_pep2, Wg_pro1, Wg_pro2, Wt_pep, Wt_pro,
      x_edge_pep, x_edge_pro,
      WppTp, WppTr, Wg1Tp, Wg2Tp, Wg1Tr, Wg2Tr, WtBp, WtBr,
      packedP, packedR);
  // 2. pretrain split-K partials
  pre_gemm<<<dim3((BLp + BLr) / 64, SPLITK), 256, 0, stream>>>(
      x_pretrain_pep, x_pretrain_pro, WppTp, WppTr, partP, partR);
  // 3. encoder (+ pretrain reduce + dinv from popcount)
  encoder_merged<<<BLp + BLr, 128, 0, stream>>>(
      x_pep, x_ss_pep, x_2_pep, x_dense_pep, W_dpep, b_dpep, mask_pep, partP,
      b_ppep, encBp, packedP, dinvP,
      x_pro, x_ss_pro, x_2_pro, x_dense_pro, W_dpro, b_dpro, mask_pro, partR,
      b_ppro, encBr, packedR, dinvR,
      E_seq, E_ss, E_two);
  // 4-7. GCN
  linT_merged<<<dim3((BLp + BLr) / 64, DG / 128), 256, 0, stream>>>(
      Wg1Tp, encBp, dinvP, bufATp, Wg1Tr, encBr, dinvR, bufATr);
  agg_merged<<<dim3(160, 9), 256, 0, stream>>>(
      packedP, bufATp, dinvP, bg_pep1, nullptr, nullptr, bufYp,
      packedR, bufATr, dinvR, bg_pro1, nullptr, nullptr, bufYr);
  linT_merged<<<dim3((BLp + BLr) / 64, DG / 128), 256, 0, stream>>>(
      Wg2Tp, bufYp, dinvP, bufATp, Wg2Tr, bufYr, dinvR, bufATr);
  agg_merged<<<dim3(160, 9), 256, 0, stream>>>(
      packedP, bufATp, dinvP, bg_pep2, encBp, mask_pep, bufYp,
      packedR, bufATr, dinvR, bg_pro2, encBr, mask_pro, bufYr);
  // 8. fct
  fct_merged<<<dim3(16, KH, 18), 256, 0, stream>>>(
      WtBp, bt_pep, bufYp, out,
      WtBr, bt_pro, bufYr, out + out_pro_off);
}

// Round 10
// 458.296 us; speedup vs baseline: 1.0227x; 1.0227x over previous
//
#include <hip/hip_runtime.h>
#include <hip/hip_bf16.h>

// Problem constants
#define BSZ 16
#define LP 128
#define LR 1024
#define DD 128
#define DG 640
#define KH 7
#define SPLITK 4

typedef __bf16 bf16x8 __attribute__((ext_vector_type(8)));
typedef __bf16 bf16x4v __attribute__((ext_vector_type(4)));
typedef float f32x4 __attribute__((ext_vector_type(4)));
typedef unsigned int uint32;

// ---------------------------------------------------------------------------
// MFMA core, bf16 A and B: 512 threads, 128(M) x 128(N) tile, BK=64,
// 8 waves each 32x64 (acc[2][4] -- identical inner loop to the r8 core).
// depth-1 prefetch. LDS = 36.9KB -> 4 blocks/CU x 8 waves = 32 waves/CU
// (hardware cap; r8's 4-wave blocks reached only 20). Same barrier count
// per K-element, same staging bytes/thread, same 72-pad LDS layout.
// ---------------------------------------------------------------------------
__device__ __forceinline__ void mfma_core_512(
    const ushort* __restrict__ Ab, int lda,
    const ushort* __restrict__ Bb, int ldb,
    int m0, int n0, int kStart, int kEnd, f32x4 (&acc)[2][4]) {
  __shared__ __align__(16) ushort As[128 * 72];
  __shared__ __align__(16) ushort Bs[128 * 72];
  int t = threadIdx.x;
  int wave = t >> 6, lane = t & 63;
  int quad = lane >> 4, l16 = lane & 15;
  int wm = (wave & 3) * 32, wn = (wave >> 2) * 64;
  int r1 = t >> 2, o1 = (t & 3) * 16;   // 4 threads/row, 16 ushorts each

  int4 a0, a1, b0, b1;
  auto load_k = [&](int k0) {
    a0 = *(const int4*)(Ab + (size_t)(m0 + r1) * lda + k0 + o1);
    a1 = *(const int4*)(Ab + (size_t)(m0 + r1) * lda + k0 + o1 + 8);
    b0 = *(const int4*)(Bb + (size_t)(n0 + r1) * ldb + k0 + o1);
    b1 = *(const int4*)(Bb + (size_t)(n0 + r1) * ldb + k0 + o1 + 8);
  };

  load_k(kStart);
  for (int k0 = kStart; k0 < kEnd; k0 += 64) {
    __syncthreads();   // previous iteration's LDS fully consumed
    *(int4*)&As[r1 * 72 + o1] = a0;
    *(int4*)&As[r1 * 72 + o1 + 8] = a1;
    *(int4*)&Bs[r1 * 72 + o1] = b0;
    *(int4*)&Bs[r1 * 72 + o1 + 8] = b1;
    __syncthreads();
    if (k0 + 64 < kEnd) load_k(k0 + 64);  // prefetch under compute
    #pragma unroll
    for (int kc = 0; kc < 2; ++kc) {
      bf16x8 af[2], bfr[4];
      #pragma unroll
      for (int fi = 0; fi < 2; ++fi)
        af[fi] = *(const bf16x8*)&As[(wm + fi * 16 + l16) * 72 + kc * 32 + quad * 8];
      #pragma unroll
      for (int fj = 0; fj < 4; ++fj)
        bfr[fj] = *(const bf16x8*)&Bs[(wn + fj * 16 + l16) * 72 + kc * 32 + quad * 8];
      #pragma unroll
      for (int fi = 0; fi < 2; ++fi)
        #pragma unroll
        for (int fj = 0; fj < 4; ++fj)
          acc[fi][fj] = __builtin_amdgcn_mfma_f32_16x16x32_bf16(
              af[fi], bfr[fj], acc[fi][fj], 0, 0, 0);
    }
  }
}

// ---------------------------------------------------------------------------
// agg core: 512 threads, 128(M=c) x 128(N=d), BK=64, A from packed bits.
// LDS = 19.5KB; 8 waves/block; bit-words fetched once per 128 d (halved).
// acc[c][d] += sum_r Ahat[r,c] * Xt[d][bcol + r]
// ---------------------------------------------------------------------------
__device__ __forceinline__ void agg_core_512(
    const uint32* __restrict__ pb, int L,
    const ushort* __restrict__ Bb, int ldb,
    int m0, int n0, f32x4 (&acc)[2][4]) {
  __shared__ __align__(16) ushort Bs[128 * 72];
  __shared__ uint32 Aw[2][128];
  int t = threadIdx.x;
  int wave = t >> 6, lane = t & 63;
  int quad = lane >> 4, l16 = lane & 15;
  int wm = (wave & 3) * 32, wn = (wave >> 2) * 64;
  int r1 = t >> 2, o1 = (t & 3) * 16;
  int half = (t >> 7) & 1, cc = t & 127;   // threads 0..255 load bit-words

  int4 b0, b1;
  uint32 w = 0;
  auto load_k = [&](int k0) {
    b0 = *(const int4*)(Bb + (size_t)(n0 + r1) * ldb + k0 + o1);
    b1 = *(const int4*)(Bb + (size_t)(n0 + r1) * ldb + k0 + o1 + 8);
    if (t < 256) w = pb[(size_t)((k0 >> 5) + half) * L + m0 + cc];
  };

  load_k(0);
  for (int k0 = 0; k0 < L; k0 += 64) {
    __syncthreads();
    *(int4*)&Bs[r1 * 72 + o1] = b0;
    *(int4*)&Bs[r1 * 72 + o1 + 8] = b1;
    if (t < 256) Aw[half][cc] = w;
    __syncthreads();
    if (k0 + 64 < L) load_k(k0 + 64);  // prefetch under compute
    #pragma unroll
    for (int kc = 0; kc < 2; ++kc) {
      bf16x8 af[2], bfr[4];
      #pragma unroll
      for (int fj = 0; fj < 4; ++fj)
        bfr[fj] = *(const bf16x8*)&Bs[(wn + fj * 16 + l16) * 72 + kc * 32 + quad * 8];
      #pragma unroll
      for (int fi = 0; fi < 2; ++fi) {
        uint32 bits = (Aw[kc][wm + fi * 16 + l16] >> (quad * 8)) & 0xffu;
        int4 p;
        p.x = (int)((((bits >> 0) & 1) ? 0x3F80u : 0u) | (((bits >> 1) & 1) ? 0x3F800000u : 0u));
        p.y = (int)((((bits >> 2) & 1) ? 0x3F80u : 0u) | (((bits >> 3) & 1) ? 0x3F800000u : 0u));
        p.z = (int)((((bits >> 4) & 1) ? 0x3F80u : 0u) | (((bits >> 5) & 1) ? 0x3F800000u : 0u));
        p.w = (int)((((bits >> 6) & 1) ? 0x3F80u : 0u) | (((bits >> 7) & 1) ? 0x3F800000u : 0u));
        af[fi] = *(bf16x8*)&p;
      }
      #pragma unroll
      for (int fi = 0; fi < 2; ++fi)
        #pragma unroll
        for (int fj = 0; fj < 4; ++fj)
          acc[fi][fj] = __builtin_amdgcn_mfma_f32_16x16x32_bf16(
              af[fi], bfr[fj], acc[fi][fj], 0, 0, 0);
    }
  }
}

// ---------------------------------------------------------------------------
// MFMA core, f32 A (converted to bf16 during staging), 64(M)x128(N), BK=64,
// depth-1 prefetch. Used only by pre_gemm (r8 verbatim).
// ---------------------------------------------------------------------------
__device__ __forceinline__ void mfma_core_f32_m64(
    const float* __restrict__ Af, int lda,
    const ushort* __restrict__ Bb, int ldb,
    int m0, int kStart, int kEnd, f32x4 (&acc)[2][4]) {
  __shared__ __align__(16) ushort As[64 * 72];
  __shared__ __align__(16) ushort Bs[128 * 72];
  int t = threadIdx.x;
  int wave = t >> 6, lane = t & 63;
  int quad = lane >> 4, l16 = lane & 15;
  int wm = (wave >> 1) * 32, wn = (wave & 1) * 64;
  int r1 = t >> 2, o1 = (t & 3) * 16;

  int4 b00, b01, b10, b11;
  float4 af32[4];

  auto load_k = [&](int k0) {
    b00 = *(const int4*)(Bb + (size_t)r1 * ldb + k0 + o1);
    b01 = *(const int4*)(Bb + (size_t)r1 * ldb + k0 + o1 + 8);
    b10 = *(const int4*)(Bb + (size_t)(r1 + 64) * ldb + k0 + o1);
    b11 = *(const int4*)(Bb + (size_t)(r1 + 64) * ldb + k0 + o1 + 8);
    #pragma unroll
    for (int s = 0; s < 4; ++s) {
      int idx = t + s * 256;
      int row = idx >> 4, c4 = (idx & 15) * 4;
      af32[s] = *(const float4*)(Af + (size_t)(m0 + row) * lda + k0 + c4);
    }
  };

  load_k(kStart);
  for (int k0 = kStart; k0 < kEnd; k0 += 64) {
    __syncthreads();
    #pragma unroll
    for (int s = 0; s < 4; ++s) {
      int idx = t + s * 256;
      int row = idx >> 4, c4 = (idx & 15) * 4;
      ushort4 u; __bf16 h;
      h = (__bf16)af32[s].x; u.x = *(ushort*)&h;
      h = (__bf16)af32[s].y; u.y = *(ushort*)&h;
      h = (__bf16)af32[s].z; u.z = *(ushort*)&h;
      h = (__bf16)af32[s].w; u.w = *(ushort*)&h;
      *(ushort4*)&As[row * 72 + c4] = u;
    }
    *(int4*)&Bs[r1 * 72 + o1] = b00;
    *(int4*)&Bs[r1 * 72 + o1 + 8] = b01;
    *(int4*)&Bs[(r1 + 64) * 72 + o1] = b10;
    *(int4*)&Bs[(r1 + 64) * 72 + o1 + 8] = b11;
    __syncthreads();
    if (k0 + 64 < kEnd) load_k(k0 + 64);  // prefetch under compute
    #pragma unroll
    for (int kc = 0; kc < 2; ++kc) {
      bf16x8 af[2], bfr[4];
      #pragma unroll
      for (int fi = 0; fi < 2; ++fi)
        af[fi] = *(const bf16x8*)&As[(wm + fi * 16 + l16) * 72 + kc * 32 + quad * 8];
      #pragma unroll
      for (int fj = 0; fj < 4; ++fj)
        bfr[fj] = *(const bf16x8*)&Bs[(wn + fj * 16 + l16) * 72 + kc * 32 + quad * 8];
      #pragma unroll
      for (int fi = 0; fi < 2; ++fi)
        #pragma unroll
        for (int fj = 0; fj < 4; ++fj)
          acc[fi][fj] = __builtin_amdgcn_mfma_f32_16x16x32_bf16(
              af[fi], bfr[fj], acc[fi][fj], 0, 0, 0);
    }
  }
}

// ---------------------------------------------------------------------------
// prep_all: weight conversions/transposes AND adjacency packing in ONE 1D
// dispatch. Block ranges:
//   [0,256)      WppT transposes  (2 x 128 tiles of 1024x128)
//   [256,1856)   Wg transposes    (4 x 400 tiles of 640x640)
//   [1856,2976)  WtB f32->bf16    (2 x 560 chunks)
//   [2976,5024)  pro pack, [5024,5088) pep pack
// ---------------------------------------------------------------------------
__device__ __forceinline__ void tr_tile(const float* __restrict__ src,
                                        __bf16* __restrict__ dst,
                                        int R, int C, int cb, int rb, int t) {
  __shared__ float T[32][33];
  int r0 = rb * 32, c0 = cb * 32;
  #pragma unroll
  for (int s = 0; s < 4; ++s) {
    int idx = t + s * 256;
    int r = idx >> 5, c = idx & 31;
    T[r][c] = src[(size_t)(r0 + r) * C + c0 + c];
  }
  __syncthreads();
  #pragma unroll
  for (int s = 0; s < 4; ++s) {
    int idx = t + s * 256;
    int c = idx >> 5, r = idx & 31;
    dst[(size_t)(c0 + c) * R + r0 + r] = (__bf16)T[r][c];
  }
}

__device__ __forceinline__ void pack_col(const float* __restrict__ adjB,
                                         uint32* __restrict__ packed,
                                         int L, int b, int rw, int c) {
  uint32 w = 0;
  int rbase = rw * 32;
  #pragma unroll 8
  for (int j = 0; j < 32; ++j) {
    float a = adjB[(size_t)(rbase + j) * L + c];
    if (a != 0.f || (rbase + j) == c) w |= (1u << j);
  }
  packed[((size_t)b * (L >> 5) + rw) * L + c] = w;
}

__global__ __launch_bounds__(256) void prep_all(
    const float* __restrict__ Wppep, const float* __restrict__ Wppro,
    const float* __restrict__ Wg1p, const float* __restrict__ Wg2p,
    const float* __restrict__ Wg1r, const float* __restrict__ Wg2r,
    const float* __restrict__ Wtp, const float* __restrict__ Wtr,
    const float* __restrict__ adjP, const float* __restrict__ adjR,
    __bf16* __restrict__ WppTp, __bf16* __restrict__ WppTr,
    __bf16* __restrict__ Wg1Tp, __bf16* __restrict__ Wg2Tp,
    __bf16* __restrict__ Wg1Tr, __bf16* __restrict__ Wg2Tr,
    __bf16* __restrict__ WtBp, __bf16* __restrict__ WtBr,
    uint32* __restrict__ packedP, uint32* __restrict__ packedR) {
  int g = blockIdx.x, t = threadIdx.x;
  if (g < 256) {
    int zi = g >> 7, bx = g & 127;
    tr_tile(zi ? Wppro : Wppep, zi ? WppTr : WppTp, 1024, 128, bx % 4, bx / 4, t);
  } else if (g < 1856) {
    int u = g - 256;
    int zi = u / 400, bx = u % 400;
    const float* src = (zi == 0) ? Wg1p : (zi == 1) ? Wg2p : (zi == 2) ? Wg1r : Wg2r;
    __bf16* dst = (zi == 0) ? Wg1Tp : (zi == 1) ? Wg2Tp : (zi == 2) ? Wg1Tr : Wg2Tr;
    tr_tile(src, dst, 640, 640, bx % 20, bx / 20, t);
  } else if (g < 2976) {
    int u = g - 1856;
    int zi = u / 560, bx = u % 560;
    const float* src = zi ? Wtr : Wtp;
    __bf16* dst = zi ? WtBr : WtBp;
    int i = bx * 256 + t;  // < 143360 float4s
    float4 v = ((const float4*)src)[i];
    bf16x4v o;
    o.x = (__bf16)v.x; o.y = (__bf16)v.y; o.z = (__bf16)v.z; o.w = (__bf16)v.w;
    ((bf16x4v*)dst)[i] = o;
  } else if (g < 5024) {
    int u = g - 2976;
    int b = u >> 7, rem = u & 127;
    int rw = rem >> 2, c = (rem & 3) * 256 + t;
    pack_col(adjR + (size_t)b * LR * LR, packedR, LR, b, rw, c);
  } else {
    int u = g - 5024;
    if (t >= LP) return;
    pack_col(adjP + (size_t)(u >> 2) * LP * LP, packedP, LP, u >> 2, u & 3, t);
  }
}

// ---------------------------------------------------------------------------
// pre_gemm merged (split-K pretrain partials): grid (288, SPLITK).
// bx<32: pep m-block bx (64 rows each); else pro m-block bx-32. by = k-slice.
// ---------------------------------------------------------------------------
__global__ __launch_bounds__(256) void pre_gemm(
    const float* __restrict__ XpP, const float* __restrict__ XpR,
    const __bf16* __restrict__ WppTp, const __bf16* __restrict__ WppTr,
    float* __restrict__ partP, float* __restrict__ partR) {
  int bx = blockIdx.x, s = blockIdx.y;
  int pep = bx < (BSZ * LP / 64);
  int m0 = (pep ? bx : bx - BSZ * LP / 64) * 64;
  const float* A = pep ? XpP : XpR;
  const ushort* B = (const ushort*)(pep ? WppTp : WppTr);
  int BL = pep ? BSZ * LP : BSZ * LR;
  float* part = (pep ? partP : partR) + (size_t)s * BL * DD;

  f32x4 acc[2][4];
  #pragma unroll
  for (int i = 0; i < 2; ++i)
    #pragma unroll
    for (int j = 0; j < 4; ++j) acc[i][j] = (f32x4){0.f, 0.f, 0.f, 0.f};
  mfma_core_f32_m64(A, 1024, B, 1024, m0, s * (1024 / SPLITK),
                    (s + 1) * (1024 / SPLITK), acc);

  int t = threadIdx.x;
  int wave = t >> 6, lane = t & 63;
  int quad = lane >> 4, l16 = lane & 15;
  int wm = (wave >> 1) * 32, wn = (wave & 1) * 64;
  #pragma unroll
  for (int fi = 0; fi < 2; ++fi)
    #pragma unroll
    for (int r = 0; r < 4; ++r) {
      int m = m0 + wm + fi * 16 + quad * 4 + r;
      #pragma unroll
      for (int fj = 0; fj < 4; ++fj) {
        int n = wn + fj * 16 + l16;
        part[(size_t)m * DD + n] = acc[fi][fj][r];
      }
    }
}

// ---------------------------------------------------------------------------
// Encoder merged: embeddings + dense matmul + pretrain-partial reduce
// + dinv from packed-bit popcount. grid (BLp + BLr, 128 threads)
// ---------------------------------------------------------------------------
__global__ __launch_bounds__(128) void encoder_merged(
    const int* __restrict__ xsP, const int* __restrict__ xssP,
    const int* __restrict__ x2P, const float* __restrict__ xdP,
    const float* __restrict__ WdP, const float* __restrict__ bdP,
    const float* __restrict__ maskP, const float* __restrict__ partP,
    const float* __restrict__ bppP, __bf16* __restrict__ encP,
    const uint32* __restrict__ packedP, float* __restrict__ dinvP,
    const int* __restrict__ xsR, const int* __restrict__ xssR,
    const int* __restrict__ x2R, const float* __restrict__ xdR,
    const float* __restrict__ WdR, const float* __restrict__ bdR,
    const float* __restrict__ maskR, const float* __restrict__ partR,
    const float* __restrict__ bppR, __bf16* __restrict__ encR,
    const uint32* __restrict__ packedR, float* __restrict__ dinvR,
    const float* __restrict__ Eseq, const float* __restrict__ Ess,
    const float* __restrict__ Etwo) {
  int gw = blockIdx.x;
  int t = threadIdx.x;
  int pep = gw < BSZ * LP;
  int row = pep ? gw : gw - BSZ * LP;
  int L = pep ? LP : LR;
  int BL = pep ? BSZ * LP : BSZ * LR;
  int Kd = pep ? 3 : 23;
  const int* xs = pep ? xsP : xsR;
  const int* xss = pep ? xssP : xssR;
  const int* x2 = pep ? x2P : x2R;
  const float* xd = pep ? xdP : xdR;
  const float* Wd = pep ? WdP : WdR;
  const float* bd = pep ? bdP : bdR;
  const float* mask = pep ? maskP : maskR;
  const float* part = pep ? partP : partR;
  const float* bpp = pep ? bppP : bppR;
  const uint32* packed = pep ? packedP : packedR;
  float* dinv = pep ? dinvP : dinvR;
  __bf16* enc = pep ? encP : encR;

  // dinv from packed popcount: wave 0, lanes 0..nw-1 (nw = L/32)
  int nw = L >> 5;
  int bb = row / L, ccol = row % L;
  uint32 wv = (t < nw) ? packed[((size_t)bb * nw + t) * L + ccol] : 0u;
  int cnt = __popc(wv);
  if (t < 64) {
    #pragma unroll
    for (int off = 16; off >= 1; off >>= 1) cnt += __shfl_down(cnt, off);
    if (t == 0) dinv[row] = rsqrtf((float)cnt);
  }

  float m = mask[row];
  int i0 = xs[row], i1 = xss[row], i2 = x2[row];
  __bf16* e = enc + (size_t)row * DG;
  e[t]        = (__bf16)(Eseq[i0 * DD + t] * m);
  e[DD + t]   = (__bf16)(Ess[i1 * DD + t] * m);
  e[2*DD + t] = (__bf16)(Etwo[i2 * DD + t] * m);
  float acc = bd[t];
  const float* xr = xd + (size_t)row * Kd;
  for (int i = 0; i < Kd; ++i) acc = fmaf(xr[i], Wd[i * DD + t], acc);
  e[3*DD + t] = (__bf16)(acc * m);
  // pretrain reduce -> cols 512..639
  float p = bpp[t];
  #pragma unroll
  for (int s = 0; s < SPLITK; ++s)
    p += part[(size_t)s * BL * DD + (size_t)row * DD + t];
  e[4*DD + t] = (__bf16)(p * m);
}

// ---------------------------------------------------------------------------
// linT merged: bufAT[d][row] = dinv[row] * sum_k src[row][k] * Wg[k][d]
// grid (144, 5) x 512 thr: bx<16 pep n-block (128 rows), else pro.
// by = m-block (d).
// ---------------------------------------------------------------------------
__global__ __launch_bounds__(512) void linT_merged(
    const __bf16* __restrict__ WgTp, const __bf16* __restrict__ srcP,
    const float* __restrict__ dinvP, __bf16* __restrict__ dstP,
    const __bf16* __restrict__ WgTr, const __bf16* __restrict__ srcR,
    const float* __restrict__ dinvR, __bf16* __restrict__ dstR) {
  int bx = blockIdx.x;
  int pep = bx < (BSZ * LP / 128);
  int n0 = (pep ? bx : bx - BSZ * LP / 128) * 128;
  int m0 = blockIdx.y * 128;
  int BL = pep ? BSZ * LP : BSZ * LR;
  const ushort* A = (const ushort*)(pep ? WgTp : WgTr);
  const ushort* B = (const ushort*)(pep ? srcP : srcR);
  const float* dinv = pep ? dinvP : dinvR;
  __bf16* dst = pep ? dstP : dstR;

  f32x4 acc[2][4];
  #pragma unroll
  for (int i = 0; i < 2; ++i)
    #pragma unroll
    for (int j = 0; j < 4; ++j) acc[i][j] = (f32x4){0.f, 0.f, 0.f, 0.f};
  mfma_core_512(A, DG, B, DG, m0, n0, 0, DG, acc);

  int t = threadIdx.x;
  int wave = t >> 6, lane = t & 63;
  int quad = lane >> 4, l16 = lane & 15;
  int wm = (wave & 3) * 32, wn = (wave >> 2) * 64;
  #pragma unroll
  for (int fi = 0; fi < 2; ++fi)
    #pragma unroll
    for (int r = 0; r < 4; ++r) {
      int m = m0 + wm + fi * 16 + quad * 4 + r;
      #pragma unroll
      for (int fj = 0; fj < 4; ++fj) {
        int n = n0 + wn + fj * 16 + l16;
        dst[(size_t)m * BL + n] = (__bf16)(acc[fi][fj][r] * dinv[n]);
      }
    }
}

// ---------------------------------------------------------------------------
// agg merged, XCD-aware grid: (80, 9) x 512 thr.
// bx encodes (b = bx/5, n0 = (bx%5)*128). by==0: pep (m0=0); else pro
// m-block by-1. Same-(b,n0) blocks differ by 80 (80%8==0) -> same XCD.
// Y[b,c,d] = relu(dinv*acc + bias[d] (+encE)) * (mask?)
// ---------------------------------------------------------------------------
__global__ __launch_bounds__(512) void agg_merged(
    const uint32* __restrict__ packedP, const __bf16* __restrict__ XtP,
    const float* __restrict__ dinvP, const float* __restrict__ biasP,
    const __bf16* __restrict__ encEP, const float* __restrict__ maskP,
    __bf16* __restrict__ YP,
    const uint32* __restrict__ packedR, const __bf16* __restrict__ XtR,
    const float* __restrict__ dinvR, const float* __restrict__ biasR,
    const __bf16* __restrict__ encER, const float* __restrict__ maskR,
    __bf16* __restrict__ YR) {
  int bx = blockIdx.x;
  int b = bx / 5;
  int n0 = (bx % 5) * 128;
  int pep = (blockIdx.y == 0);
  int L = pep ? LP : LR;
  int BL = BSZ * L;
  int m0 = pep ? 0 : (blockIdx.y - 1) * 128;
  const uint32* pb = (pep ? packedP : packedR) + (size_t)b * (L >> 5) * L;
  const ushort* Bb = (const ushort*)(pep ? XtP : XtR) + (size_t)b * L;
  const float* dinv = pep ? dinvP : dinvR;
  const float* bias = pep ? biasP : biasR;
  const __bf16* encE = pep ? encEP : encER;
  const float* mask = pep ? maskP : maskR;
  __bf16* Y = pep ? YP : YR;

  f32x4 acc[2][4];
  #pragma unroll
  for (int i = 0; i < 2; ++i)
    #pragma unroll
    for (int j = 0; j < 4; ++j) acc[i][j] = (f32x4){0.f, 0.f, 0.f, 0.f};
  agg_core_512(pb, L, Bb, BL, m0, n0, acc);

  int t = threadIdx.x;
  int wave = t >> 6, lane = t & 63;
  int quad = lane >> 4, l16 = lane & 15;
  int wm = (wave & 3) * 32, wn = (wave >> 2) * 64;
  int gRow = b * L;
  #pragma unroll
  for (int fi = 0; fi < 2; ++fi)
    #pragma unroll
    for (int r = 0; r < 4; ++r) {
      int m = m0 + wm + fi * 16 + quad * 4 + r;
      int gi = gRow + m;
      float di = dinv[gi];
      float rm = mask ? mask[gi] : 1.f;
      #pragma unroll
      for (int fj = 0; fj < 4; ++fj) {
        int n = n0 + wn + fj * 16 + l16;
        float v = acc[fi][fj][r] * di + bias[n];
        if (encE) v += (float)encE[(size_t)gi * DG + n];
        v = fmaxf(v, 0.f);
        v *= rm;
        Y[(size_t)gi * DG + n] = (__bf16)v;
      }
    }
}

// ---------------------------------------------------------------------------
// fct merged: grid (8, 7, 18) x 512 thr. bz<16: pro (b=bz, n0=bx*128 over
// LR); bz>=16: pep (chunk=(bz-16)*8+bx over BLp flattened, 128 each). f32 out.
// ---------------------------------------------------------------------------
__global__ __launch_bounds__(512) void fct_merged(
    const __bf16* __restrict__ WtBp, const float* __restrict__ btp,
    const __bf16* __restrict__ Yp, float* __restrict__ outP,
    const __bf16* __restrict__ WtBr, const float* __restrict__ btr,
    const __bf16* __restrict__ Yr, float* __restrict__ outR) {
  int kh = blockIdx.y;
  int pro = (blockIdx.z < 16);
  const ushort* A;
  const ushort* B;
  const float* bt;
  int n0;
  if (pro) {
    A = (const ushort*)(WtBr + (size_t)kh * DD * DG);
    B = (const ushort*)(Yr + (size_t)blockIdx.z * LR * DG);
    bt = btr;
    n0 = blockIdx.x * 128;
  } else {
    A = (const ushort*)(WtBp + (size_t)kh * DD * DG);
    B = (const ushort*)Yp;
    bt = btp;
    n0 = ((blockIdx.z - 16) * 8 + blockIdx.x) * 128;
  }

  f32x4 acc[2][4];
  #pragma unroll
  for (int i = 0; i < 2; ++i)
    #pragma unroll
    for (int j = 0; j < 4; ++j) acc[i][j] = (f32x4){0.f, 0.f, 0.f, 0.f};
  mfma_core_512(A, DG, B, DG, 0, n0, 0, DG, acc);

  int t = threadIdx.x;
  int wave = t >> 6, lane = t & 63;
  int quad = lane >> 4, l16 = lane & 15;
  int wm = (wave & 3) * 32, wn = (wave >> 2) * 64;
  #pragma unroll
  for (int fi = 0; fi < 2; ++fi)
    #pragma unroll
    for (int r = 0; r < 4; ++r) {
      int m = wm + fi * 16 + quad * 4 + r;
      float bb = bt[kh * DD + m];
      #pragma unroll
      for (int fj = 0; fj < 4; ++fj) {
        int n = n0 + wn + fj * 16 + l16;
        float v = fmaxf(acc[fi][fj][r] + bb, 0.f);
        if (pro) {
          outR[((size_t)(kh * BSZ + blockIdx.z) * DD + m) * LR + n] = v;
        } else {
          int b = n >> 7, l = n & 127;
          outP[((size_t)(kh * BSZ + b) * DD + m) * LP + l] = v;
        }
      }
    }
}

// ---------------------------------------------------------------------------
extern "C" void kernel_launch(void* const* d_in, const int* in_sizes, int n_in,
                              void* d_out, int out_size, void* d_ws, size_t ws_size,
                              hipStream_t stream) {
  const int*   x_pep          = (const int*)d_in[0];
  const int*   x_ss_pep       = (const int*)d_in[1];
  const int*   x_2_pep        = (const int*)d_in[2];
  const float* x_dense_pep    = (const float*)d_in[3];
  const float* x_pretrain_pep = (const float*)d_in[4];
  const int*   x_pro          = (const int*)d_in[5];
  const int*   x_ss_pro       = (const int*)d_in[6];
  const int*   x_2_pro        = (const int*)d_in[7];
  const float* x_dense_pro    = (const float*)d_in[8];
  const float* x_pretrain_pro = (const float*)d_in[9];
  const float* x_edge_pep     = (const float*)d_in[10];
  const float* x_edge_pro     = (const float*)d_in[11];
  const float* mask_pep       = (const float*)d_in[12];
  const float* mask_pro       = (const float*)d_in[13];
  const float* E_seq          = (const float*)d_in[14];
  const float* E_ss           = (const float*)d_in[15];
  const float* E_two          = (const float*)d_in[16];
  const float* W_dpep         = (const float*)d_in[17];
  const float* b_dpep         = (const float*)d_in[18];
  const float* W_dpro         = (const float*)d_in[19];
  const float* b_dpro         = (const float*)d_in[20];
  const float* W_ppep         = (const float*)d_in[21];
  const float* b_ppep         = (const float*)d_in[22];
  const float* W_ppro         = (const float*)d_in[23];
  const float* b_ppro         = (const float*)d_in[24];
  const float* Wg_pep1        = (const float*)d_in[25];
  const float* bg_pep1        = (const float*)d_in[26];
  const float* Wg_pep2        = (const float*)d_in[27];
  const float* bg_pep2        = (const float*)d_in[28];
  const float* Wg_pro1        = (const float*)d_in[29];
  const float* bg_pro1        = (const float*)d_in[30];
  const float* Wg_pro2        = (const float*)d_in[31];
  const float* bg_pro2        = (const float*)d_in[32];
  const float* Wt_pep         = (const float*)d_in[33];
  const float* bt_pep         = (const float*)d_in[34];
  const float* Wt_pro         = (const float*)d_in[35];
  const float* bt_pro         = (const float*)d_in[36];

  float* out = (float*)d_out;
  const int BLp = BSZ * LP;   // 2048
  const int BLr = BSZ * LR;   // 16384
  const size_t out_pro_off = (size_t)KH * BSZ * DD * LP;

  // Workspace layout (~117 MB)
  char* w = (char*)d_ws;
  __bf16* encBp  = (__bf16*)w; w += (size_t)BLp * DG * 2;
  __bf16* encBr  = (__bf16*)w; w += (size_t)BLr * DG * 2;
  __bf16* bufATp = (__bf16*)w; w += (size_t)DG * BLp * 2;
  __bf16* bufATr = (__bf16*)w; w += (size_t)DG * BLr * 2;
  __bf16* bufYp  = (__bf16*)w; w += (size_t)BLp * DG * 2;
  __bf16* bufYr  = (__bf16*)w; w += (size_t)BLr * DG * 2;
  __bf16* WppTp  = (__bf16*)w; w += (size_t)DD * 1024 * 2;
  __bf16* WppTr  = (__bf16*)w; w += (size_t)DD * 1024 * 2;
  __bf16* Wg1Tp  = (__bf16*)w; w += (size_t)DG * DG * 2;
  __bf16* Wg2Tp  = (__bf16*)w; w += (size_t)DG * DG * 2;
  __bf16* Wg1Tr  = (__bf16*)w; w += (size_t)DG * DG * 2;
  __bf16* Wg2Tr  = (__bf16*)w; w += (size_t)DG * DG * 2;
  __bf16* WtBp   = (__bf16*)w; w += (size_t)KH * DD * DG * 2;
  __bf16* WtBr   = (__bf16*)w; w += (size_t)KH * DD * DG * 2;
  uint32* packedP = (uint32*)w; w += (size_t)BSZ * (LP / 32) * LP * 4;
  uint32* packedR = (uint32*)w; w += (size_t)BSZ * (LR / 32) * LR * 4;
  float* dinvP = (float*)w; w += (size_t)BLp * 4;
  float* dinvR = (float*)w; w += (size_t)BLr * 4;
  float* partP = (float*)w; w += (size_t)SPLITK * BLp * DD * 4;
  float* partR = (float*)w; w += (size_t)SPLITK * BLr * DD * 4;

  // 1. weights + adjacency pack (single merged dispatch, no atomics)
  prep_all<<<5088, 256, 0, stream>>>(
      W_ppep, W_ppro, Wg_pep1, Wg_pep2, Wg_pro1, Wg_pro2, Wt_pep, Wt_pro,
      x_edge_pep, x_edge_pro,
      WppTp, WppTr, Wg1Tp, Wg2Tp, Wg1Tr, Wg2Tr, WtBp, WtBr,
      packedP, packedR);
  // 2. pretrain split-K partials
  pre_gemm<<<dim3((BLp + BLr) / 64, SPLITK), 256, 0, stream>>>(
      x_pretrain_pep, x_pretrain_pro, WppTp, WppTr, partP, partR);
  // 3. encoder (+ pretrain reduce + dinv from popcount)
  encoder_merged<<<BLp + BLr, 128, 0, stream>>>(
      x_pep, x_ss_pep, x_2_pep, x_dense_pep, W_dpep, b_dpep, mask_pep, partP,
      b_ppep, encBp, packedP, dinvP,
      x_pro, x_ss_pro, x_2_pro, x_dense_pro, W_dpro, b_dpro, mask_pro, partR,
      b_ppro, encBr, packedR, dinvR,
      E_seq, E_ss, E_two);
  // 4-7. GCN (512-thread 128x128 cores)
  linT_merged<<<dim3((BLp + BLr) / 128, DG / 128), 512, 0, stream>>>(
      Wg1Tp, encBp, dinvP, bufATp, Wg1Tr, encBr, dinvR, bufATr);
  agg_merged<<<dim3(80, 9), 512, 0, stream>>>(
      packedP, bufATp, dinvP, bg_pep1, nullptr, nullptr, bufYp,
      packedR, bufATr, dinvR, bg_pro1, nullptr, nullptr, bufYr);
  linT_merged<<<dim3((BLp + BLr) / 128, DG / 128), 512, 0, stream>>>(
      Wg2Tp, bufYp, dinvP, bufATp, Wg2Tr, bufYr, dinvR, bufATr);
  agg_merged<<<dim3(80, 9), 512, 0, stream>>>(
      packedP, bufATp, dinvP, bg_pep2, encBp, mask_pep, bufYp,
      packedR, bufATr, dinvR, bg_pro2, encBr, mask_pro, bufYr);
  // 8. fct
  fct_merged<<<dim3(8, KH, 18), 512, 0, stream>>>(
      WtBp, bt_pep, bufYp, out,
      WtBr, bt_pro, bufYr, out + out_pro_off);
}

// Round 11
// 445.693 us; speedup vs baseline: 1.0517x; 1.0283x over previous
//
#include <hip/hip_runtime.h>
#include <hip/hip_bf16.h>

// Problem constants
#define BSZ 16
#define LP 128
#define LR 1024
#define DD 128
#define DG 640
#define KH 7
#define SPLITK 4

typedef __bf16 bf16x8 __attribute__((ext_vector_type(8)));
typedef __bf16 bf16x4v __attribute__((ext_vector_type(4)));
typedef float f32x4 __attribute__((ext_vector_type(4)));
typedef unsigned int uint32;

// ---------------------------------------------------------------------------
// MFMA core, bf16 A and B: 128(M) x 64(N) tile, BK=64, 4 waves (each 32x64),
// depth-1 prefetch (r6-proven schedule: loads for iter k+1 issued under
// compute(k)). 27.6KB LDS -> 5 blocks/CU; latency hidden by cross-block TLP.
// Session ledger: depth-2 (r3/r7), BK=32 (r9), 8-wave 128x128 (r10), A-from-L2
// (r5) all measured WORSE; this exact schedule is the verified optimum.
// ---------------------------------------------------------------------------
__device__ __forceinline__ void mfma_core_n64(
    const ushort* __restrict__ Ab, int lda,
    const ushort* __restrict__ Bb, int ldb,
    int m0, int n0, int kStart, int kEnd, f32x4 (&acc)[2][4]) {
  __shared__ __align__(16) ushort As[128 * 72];
  __shared__ __align__(16) ushort Bs[64 * 72];
  int t = threadIdx.x;
  int wave = t >> 6, lane = t & 63;
  int quad = lane >> 4, l16 = lane & 15;
  int wm = wave * 32;
  int r1 = t >> 2, o1 = (t & 3) * 16;

  int4 a0, a1, a2, a3, bb0, bb1;
  auto load_k = [&](int k0) {
    a0 = *(const int4*)(Ab + (size_t)(m0 + r1) * lda + k0 + o1);
    a1 = *(const int4*)(Ab + (size_t)(m0 + r1) * lda + k0 + o1 + 8);
    a2 = *(const int4*)(Ab + (size_t)(m0 + r1 + 64) * lda + k0 + o1);
    a3 = *(const int4*)(Ab + (size_t)(m0 + r1 + 64) * lda + k0 + o1 + 8);
    bb0 = *(const int4*)(Bb + (size_t)(n0 + r1) * ldb + k0 + o1);
    bb1 = *(const int4*)(Bb + (size_t)(n0 + r1) * ldb + k0 + o1 + 8);
  };

  load_k(kStart);
  for (int k0 = kStart; k0 < kEnd; k0 += 64) {
    __syncthreads();   // previous iteration's LDS fully consumed
    *(int4*)&As[r1 * 72 + o1] = a0;
    *(int4*)&As[r1 * 72 + o1 + 8] = a1;
    *(int4*)&As[(r1 + 64) * 72 + o1] = a2;
    *(int4*)&As[(r1 + 64) * 72 + o1 + 8] = a3;
    *(int4*)&Bs[r1 * 72 + o1] = bb0;
    *(int4*)&Bs[r1 * 72 + o1 + 8] = bb1;
    __syncthreads();
    if (k0 + 64 < kEnd) load_k(k0 + 64);  // prefetch under compute
    #pragma unroll
    for (int kc = 0; kc < 2; ++kc) {
      bf16x8 af[2], bfr[4];
      #pragma unroll
      for (int fi = 0; fi < 2; ++fi)
        af[fi] = *(const bf16x8*)&As[(wm + fi * 16 + l16) * 72 + kc * 32 + quad * 8];
      #pragma unroll
      for (int fj = 0; fj < 4; ++fj)
        bfr[fj] = *(const bf16x8*)&Bs[(fj * 16 + l16) * 72 + kc * 32 + quad * 8];
      #pragma unroll
      for (int fi = 0; fi < 2; ++fi)
        #pragma unroll
        for (int fj = 0; fj < 4; ++fj)
          acc[fi][fj] = __builtin_amdgcn_mfma_f32_16x16x32_bf16(
              af[fi], bfr[fj], acc[fi][fj], 0, 0, 0);
    }
  }
}

// ---------------------------------------------------------------------------
// agg core: A built in-register from packed adjacency bits, 128(M)x64(N),
// BK=64, depth-1 prefetch. LDS = 10KB -> 8 blocks/CU (full wave occupancy).
// acc[c][d] += sum_r Ahat[r,c] * Xt[d][bcol + r]
// ---------------------------------------------------------------------------
__device__ __forceinline__ void agg_core_n64(
    const uint32* __restrict__ pb, int L,
    const ushort* __restrict__ Bb, int ldb,
    int m0, int n0, f32x4 (&acc)[2][4]) {
  __shared__ __align__(16) ushort Bs[64 * 72];
  __shared__ uint32 Aw[2][128];
  int t = threadIdx.x;
  int wave = t >> 6, lane = t & 63;
  int quad = lane >> 4, l16 = lane & 15;
  int wm = wave * 32;
  int r1 = t >> 2, o1 = (t & 3) * 16;
  int half = t >> 7, cc = t & 127;

  int4 bb0, bb1;
  uint32 w;
  auto load_k = [&](int k0) {
    bb0 = *(const int4*)(Bb + (size_t)(n0 + r1) * ldb + k0 + o1);
    bb1 = *(const int4*)(Bb + (size_t)(n0 + r1) * ldb + k0 + o1 + 8);
    w = pb[(size_t)((k0 >> 5) + half) * L + m0 + cc];
  };

  load_k(0);
  for (int k0 = 0; k0 < L; k0 += 64) {
    __syncthreads();
    *(int4*)&Bs[r1 * 72 + o1] = bb0;
    *(int4*)&Bs[r1 * 72 + o1 + 8] = bb1;
    Aw[half][cc] = w;
    __syncthreads();
    if (k0 + 64 < L) load_k(k0 + 64);  // prefetch under compute
    #pragma unroll
    for (int kc = 0; kc < 2; ++kc) {
      bf16x8 af[2], bfr[4];
      #pragma unroll
      for (int fj = 0; fj < 4; ++fj)
        bfr[fj] = *(const bf16x8*)&Bs[(fj * 16 + l16) * 72 + kc * 32 + quad * 8];
      #pragma unroll
      for (int fi = 0; fi < 2; ++fi) {
        uint32 bits = (Aw[kc][wm + fi * 16 + l16] >> (quad * 8)) & 0xffu;
        int4 p;
        p.x = (int)((((bits >> 0) & 1) ? 0x3F80u : 0u) | (((bits >> 1) & 1) ? 0x3F800000u : 0u));
        p.y = (int)((((bits >> 2) & 1) ? 0x3F80u : 0u) | (((bits >> 3) & 1) ? 0x3F800000u : 0u));
        p.z = (int)((((bits >> 4) & 1) ? 0x3F80u : 0u) | (((bits >> 5) & 1) ? 0x3F800000u : 0u));
        p.w = (int)((((bits >> 6) & 1) ? 0x3F80u : 0u) | (((bits >> 7) & 1) ? 0x3F800000u : 0u));
        af[fi] = *(bf16x8*)&p;
      }
      #pragma unroll
      for (int fi = 0; fi < 2; ++fi)
        #pragma unroll
        for (int fj = 0; fj < 4; ++fj)
          acc[fi][fj] = __builtin_amdgcn_mfma_f32_16x16x32_bf16(
              af[fi], bfr[fj], acc[fi][fj], 0, 0, 0);
    }
  }
}

// ---------------------------------------------------------------------------
// MFMA core, f32 A (converted to bf16 during staging), 64(M)x128(N), BK=64,
// depth-1 prefetch. M64 doubles pre_gemm's grid (1152 blocks, 4.5/CU).
// ---------------------------------------------------------------------------
__device__ __forceinline__ void mfma_core_f32_m64(
    const float* __restrict__ Af, int lda,
    const ushort* __restrict__ Bb, int ldb,
    int m0, int kStart, int kEnd, f32x4 (&acc)[2][4]) {
  __shared__ __align__(16) ushort As[64 * 72];
  __shared__ __align__(16) ushort Bs[128 * 72];
  int t = threadIdx.x;
  int wave = t >> 6, lane = t & 63;
  int quad = lane >> 4, l16 = lane & 15;
  int wm = (wave >> 1) * 32, wn = (wave & 1) * 64;
  int r1 = t >> 2, o1 = (t & 3) * 16;

  int4 b00, b01, b10, b11;
  float4 af32[4];

  auto load_k = [&](int k0) {
    b00 = *(const int4*)(Bb + (size_t)r1 * ldb + k0 + o1);
    b01 = *(const int4*)(Bb + (size_t)r1 * ldb + k0 + o1 + 8);
    b10 = *(const int4*)(Bb + (size_t)(r1 + 64) * ldb + k0 + o1);
    b11 = *(const int4*)(Bb + (size_t)(r1 + 64) * ldb + k0 + o1 + 8);
    #pragma unroll
    for (int s = 0; s < 4; ++s) {
      int idx = t + s * 256;
      int row = idx >> 4, c4 = (idx & 15) * 4;
      af32[s] = *(const float4*)(Af + (size_t)(m0 + row) * lda + k0 + c4);
    }
  };

  load_k(kStart);
  for (int k0 = kStart; k0 < kEnd; k0 += 64) {
    __syncthreads();
    #pragma unroll
    for (int s = 0; s < 4; ++s) {
      int idx = t + s * 256;
      int row = idx >> 4, c4 = (idx & 15) * 4;
      ushort4 u; __bf16 h;
      h = (__bf16)af32[s].x; u.x = *(ushort*)&h;
      h = (__bf16)af32[s].y; u.y = *(ushort*)&h;
      h = (__bf16)af32[s].z; u.z = *(ushort*)&h;
      h = (__bf16)af32[s].w; u.w = *(ushort*)&h;
      *(ushort4*)&As[row * 72 + c4] = u;
    }
    *(int4*)&Bs[r1 * 72 + o1] = b00;
    *(int4*)&Bs[r1 * 72 + o1 + 8] = b01;
    *(int4*)&Bs[(r1 + 64) * 72 + o1] = b10;
    *(int4*)&Bs[(r1 + 64) * 72 + o1 + 8] = b11;
    __syncthreads();
    if (k0 + 64 < kEnd) load_k(k0 + 64);  // prefetch under compute
    #pragma unroll
    for (int kc = 0; kc < 2; ++kc) {
      bf16x8 af[2], bfr[4];
      #pragma unroll
      for (int fi = 0; fi < 2; ++fi)
        af[fi] = *(const bf16x8*)&As[(wm + fi * 16 + l16) * 72 + kc * 32 + quad * 8];
      #pragma unroll
      for (int fj = 0; fj < 4; ++fj)
        bfr[fj] = *(const bf16x8*)&Bs[(wn + fj * 16 + l16) * 72 + kc * 32 + quad * 8];
      #pragma unroll
      for (int fi = 0; fi < 2; ++fi)
        #pragma unroll
        for (int fj = 0; fj < 4; ++fj)
          acc[fi][fj] = __builtin_amdgcn_mfma_f32_16x16x32_bf16(
              af[fi], bfr[fj], acc[fi][fj], 0, 0, 0);
    }
  }
}

// ---------------------------------------------------------------------------
// prep_all: weight conversions/transposes AND adjacency packing in ONE 1D
// dispatch. Block ranges:
//   [0,256)      WppT transposes  (2 x 128 tiles of 1024x128)
//   [256,1856)   Wg transposes    (4 x 400 tiles of 640x640)
//   [1856,2976)  WtB f32->bf16    (2 x 560 chunks)
//   [2976,5024)  pro pack, [5024,5088) pep pack
// ---------------------------------------------------------------------------
__device__ __forceinline__ void tr_tile(const float* __restrict__ src,
                                        __bf16* __restrict__ dst,
                                        int R, int C, int cb, int rb, int t) {
  __shared__ float T[32][33];
  int r0 = rb * 32, c0 = cb * 32;
  #pragma unroll
  for (int s = 0; s < 4; ++s) {
    int idx = t + s * 256;
    int r = idx >> 5, c = idx & 31;
    T[r][c] = src[(size_t)(r0 + r) * C + c0 + c];
  }
  __syncthreads();
  #pragma unroll
  for (int s = 0; s < 4; ++s) {
    int idx = t + s * 256;
    int c = idx >> 5, r = idx & 31;
    dst[(size_t)(c0 + c) * R + r0 + r] = (__bf16)T[r][c];
  }
}

__device__ __forceinline__ void pack_col(const float* __restrict__ adjB,
                                         uint32* __restrict__ packed,
                                         int L, int b, int rw, int c) {
  uint32 w = 0;
  int rbase = rw * 32;
  #pragma unroll 8
  for (int j = 0; j < 32; ++j) {
    float a = adjB[(size_t)(rbase + j) * L + c];
    if (a != 0.f || (rbase + j) == c) w |= (1u << j);
  }
  packed[((size_t)b * (L >> 5) + rw) * L + c] = w;
}

__global__ __launch_bounds__(256) void prep_all(
    const float* __restrict__ Wppep, const float* __restrict__ Wppro,
    const float* __restrict__ Wg1p, const float* __restrict__ Wg2p,
    const float* __restrict__ Wg1r, const float* __restrict__ Wg2r,
    const float* __restrict__ Wtp, const float* __restrict__ Wtr,
    const float* __restrict__ adjP, const float* __restrict__ adjR,
    __bf16* __restrict__ WppTp, __bf16* __restrict__ WppTr,
    __bf16* __restrict__ Wg1Tp, __bf16* __restrict__ Wg2Tp,
    __bf16* __restrict__ Wg1Tr, __bf16* __restrict__ Wg2Tr,
    __bf16* __restrict__ WtBp, __bf16* __restrict__ WtBr,
    uint32* __restrict__ packedP, uint32* __restrict__ packedR) {
  int g = blockIdx.x, t = threadIdx.x;
  if (g < 256) {
    int zi = g >> 7, bx = g & 127;
    tr_tile(zi ? Wppro : Wppep, zi ? WppTr : WppTp, 1024, 128, bx % 4, bx / 4, t);
  } else if (g < 1856) {
    int u = g - 256;
    int zi = u / 400, bx = u % 400;
    const float* src = (zi == 0) ? Wg1p : (zi == 1) ? Wg2p : (zi == 2) ? Wg1r : Wg2r;
    __bf16* dst = (zi == 0) ? Wg1Tp : (zi == 1) ? Wg2Tp : (zi == 2) ? Wg1Tr : Wg2Tr;
    tr_tile(src, dst, 640, 640, bx % 20, bx / 20, t);
  } else if (g < 2976) {
    int u = g - 1856;
    int zi = u / 560, bx = u % 560;
    const float* src = zi ? Wtr : Wtp;
    __bf16* dst = zi ? WtBr : WtBp;
    int i = bx * 256 + t;  // < 143360 float4s
    float4 v = ((const float4*)src)[i];
    bf16x4v o;
    o.x = (__bf16)v.x; o.y = (__bf16)v.y; o.z = (__bf16)v.z; o.w = (__bf16)v.w;
    ((bf16x4v*)dst)[i] = o;
  } else if (g < 5024) {
    int u = g - 2976;
    int b = u >> 7, rem = u & 127;
    int rw = rem >> 2, c = (rem & 3) * 256 + t;
    pack_col(adjR + (size_t)b * LR * LR, packedR, LR, b, rw, c);
  } else {
    int u = g - 5024;
    if (t >= LP) return;
    pack_col(adjP + (size_t)(u >> 2) * LP * LP, packedP, LP, u >> 2, u & 3, t);
  }
}

// ---------------------------------------------------------------------------
// pre_gemm merged (split-K pretrain partials): grid (288, SPLITK).
// bx<32: pep m-block bx (64 rows each); else pro m-block bx-32. by = k-slice.
// ---------------------------------------------------------------------------
__global__ __launch_bounds__(256) void pre_gemm(
    const float* __restrict__ XpP, const float* __restrict__ XpR,
    const __bf16* __restrict__ WppTp, const __bf16* __restrict__ WppTr,
    float* __restrict__ partP, float* __restrict__ partR) {
  int bx = blockIdx.x, s = blockIdx.y;
  int pep = bx < (BSZ * LP / 64);
  int m0 = (pep ? bx : bx - BSZ * LP / 64) * 64;
  const float* A = pep ? XpP : XpR;
  const ushort* B = (const ushort*)(pep ? WppTp : WppTr);
  int BL = pep ? BSZ * LP : BSZ * LR;
  float* part = (pep ? partP : partR) + (size_t)s * BL * DD;

  f32x4 acc[2][4];
  #pragma unroll
  for (int i = 0; i < 2; ++i)
    #pragma unroll
    for (int j = 0; j < 4; ++j) acc[i][j] = (f32x4){0.f, 0.f, 0.f, 0.f};
  mfma_core_f32_m64(A, 1024, B, 1024, m0, s * (1024 / SPLITK),
                    (s + 1) * (1024 / SPLITK), acc);

  int t = threadIdx.x;
  int wave = t >> 6, lane = t & 63;
  int quad = lane >> 4, l16 = lane & 15;
  int wm = (wave >> 1) * 32, wn = (wave & 1) * 64;
  #pragma unroll
  for (int fi = 0; fi < 2; ++fi)
    #pragma unroll
    for (int r = 0; r < 4; ++r) {
      int m = m0 + wm + fi * 16 + quad * 4 + r;
      #pragma unroll
      for (int fj = 0; fj < 4; ++fj) {
        int n = wn + fj * 16 + l16;
        part[(size_t)m * DD + n] = acc[fi][fj][r];
      }
    }
}

// ---------------------------------------------------------------------------
// Encoder merged: embeddings + dense matmul + pretrain-partial reduce
// + dinv from packed-bit popcount. grid (BLp + BLr, 128 threads)
// ---------------------------------------------------------------------------
__global__ __launch_bounds__(128) void encoder_merged(
    const int* __restrict__ xsP, const int* __restrict__ xssP,
    const int* __restrict__ x2P, const float* __restrict__ xdP,
    const float* __restrict__ WdP, const float* __restrict__ bdP,
    const float* __restrict__ maskP, const float* __restrict__ partP,
    const float* __restrict__ bppP, __bf16* __restrict__ encP,
    const uint32* __restrict__ packedP, float* __restrict__ dinvP,
    const int* __restrict__ xsR, const int* __restrict__ xssR,
    const int* __restrict__ x2R, const float* __restrict__ xdR,
    const float* __restrict__ WdR, const float* __restrict__ bdR,
    const float* __restrict__ maskR, const float* __restrict__ partR,
    const float* __restrict__ bppR, __bf16* __restrict__ encR,
    const uint32* __restrict__ packedR, float* __restrict__ dinvR,
    const float* __restrict__ Eseq, const float* __restrict__ Ess,
    const float* __restrict__ Etwo) {
  int gw = blockIdx.x;
  int t = threadIdx.x;
  int pep = gw < BSZ * LP;
  int row = pep ? gw : gw - BSZ * LP;
  int L = pep ? LP : LR;
  int BL = pep ? BSZ * LP : BSZ * LR;
  int Kd = pep ? 3 : 23;
  const int* xs = pep ? xsP : xsR;
  const int* xss = pep ? xssP : xssR;
  const int* x2 = pep ? x2P : x2R;
  const float* xd = pep ? xdP : xdR;
  const float* Wd = pep ? WdP : WdR;
  const float* bd = pep ? bdP : bdR;
  const float* mask = pep ? maskP : maskR;
  const float* part = pep ? partP : partR;
  const float* bpp = pep ? bppP : bppR;
  const uint32* packed = pep ? packedP : packedR;
  float* dinv = pep ? dinvP : dinvR;
  __bf16* enc = pep ? encP : encR;

  // dinv from packed popcount: wave 0, lanes 0..nw-1 (nw = L/32)
  int nw = L >> 5;
  int bb = row / L, ccol = row % L;
  uint32 wv = (t < nw) ? packed[((size_t)bb * nw + t) * L + ccol] : 0u;
  int cnt = __popc(wv);
  if (t < 64) {
    #pragma unroll
    for (int off = 16; off >= 1; off >>= 1) cnt += __shfl_down(cnt, off);
    if (t == 0) dinv[row] = rsqrtf((float)cnt);
  }

  float m = mask[row];
  int i0 = xs[row], i1 = xss[row], i2 = x2[row];
  __bf16* e = enc + (size_t)row * DG;
  e[t]        = (__bf16)(Eseq[i0 * DD + t] * m);
  e[DD + t]   = (__bf16)(Ess[i1 * DD + t] * m);
  e[2*DD + t] = (__bf16)(Etwo[i2 * DD + t] * m);
  float acc = bd[t];
  const float* xr = xd + (size_t)row * Kd;
  for (int i = 0; i < Kd; ++i) acc = fmaf(xr[i], Wd[i * DD + t], acc);
  e[3*DD + t] = (__bf16)(acc * m);
  // pretrain reduce -> cols 512..639
  float p = bpp[t];
  #pragma unroll
  for (int s = 0; s < SPLITK; ++s)
    p += part[(size_t)s * BL * DD + (size_t)row * DD + t];
  e[4*DD + t] = (__bf16)(p * m);
}

// ---------------------------------------------------------------------------
// linT merged: bufAT[d][row] = dinv[row] * sum_k src[row][k] * Wg[k][d]
// grid (288, 5): bx<32 pep n-block (64 rows each), else pro. by = m-block (d).
// ---------------------------------------------------------------------------
__global__ __launch_bounds__(256) void linT_merged(
    const __bf16* __restrict__ WgTp, const __bf16* __restrict__ srcP,
    const float* __restrict__ dinvP, __bf16* __restrict__ dstP,
    const __bf16* __restrict__ WgTr, const __bf16* __restrict__ srcR,
    const float* __restrict__ dinvR, __bf16* __restrict__ dstR) {
  int bx = blockIdx.x;
  int pep = bx < (BSZ * LP / 64);
  int n0 = (pep ? bx : bx - BSZ * LP / 64) * 64;
  int m0 = blockIdx.y * 128;
  int BL = pep ? BSZ * LP : BSZ * LR;
  const ushort* A = (const ushort*)(pep ? WgTp : WgTr);
  const ushort* B = (const ushort*)(pep ? srcP : srcR);
  const float* dinv = pep ? dinvP : dinvR;
  __bf16* dst = pep ? dstP : dstR;

  f32x4 acc[2][4];
  #pragma unroll
  for (int i = 0; i < 2; ++i)
    #pragma unroll
    for (int j = 0; j < 4; ++j) acc[i][j] = (f32x4){0.f, 0.f, 0.f, 0.f};
  mfma_core_n64(A, DG, B, DG, m0, n0, 0, DG, acc);

  int t = threadIdx.x;
  int wave = t >> 6, lane = t & 63;
  int quad = lane >> 4, l16 = lane & 15;
  int wm = wave * 32;
  #pragma unroll
  for (int fi = 0; fi < 2; ++fi)
    #pragma unroll
    for (int r = 0; r < 4; ++r) {
      int m = m0 + wm + fi * 16 + quad * 4 + r;
      #pragma unroll
      for (int fj = 0; fj < 4; ++fj) {
        int n = n0 + fj * 16 + l16;
        dst[(size_t)m * BL + n] = (__bf16)(acc[fi][fj][r] * dinv[n]);
      }
    }
}

// ---------------------------------------------------------------------------
// agg merged, XCD-aware grid: (160, 9).
// bx encodes (b = bx/10, n0 = (bx%10)*64). by==0: pep (m0=0); else pro
// m-block by-1. Y[b,c,d] = relu(dinv*acc + bias[d] (+encE)) * (mask?)
// ---------------------------------------------------------------------------
__global__ __launch_bounds__(256) void agg_merged(
    const uint32* __restrict__ packedP, const __bf16* __restrict__ XtP,
    const float* __restrict__ dinvP, const float* __restrict__ biasP,
    const __bf16* __restrict__ encEP, const float* __restrict__ maskP,
    __bf16* __restrict__ YP,
    const uint32* __restrict__ packedR, const __bf16* __restrict__ XtR,
    const float* __restrict__ dinvR, const float* __restrict__ biasR,
    const __bf16* __restrict__ encER, const float* __restrict__ maskR,
    __bf16* __restrict__ YR) {
  int bx = blockIdx.x;
  int b = bx / 10;
  int n0 = (bx % 10) * 64;
  int pep = (blockIdx.y == 0);
  int L = pep ? LP : LR;
  int BL = BSZ * L;
  int m0 = pep ? 0 : (blockIdx.y - 1) * 128;
  const uint32* pb = (pep ? packedP : packedR) + (size_t)b * (L >> 5) * L;
  const ushort* Bb = (const ushort*)(pep ? XtP : XtR) + (size_t)b * L;
  const float* dinv = pep ? dinvP : dinvR;
  const float* bias = pep ? biasP : biasR;
  const __bf16* encE = pep ? encEP : encER;
  const float* mask = pep ? maskP : maskR;
  __bf16* Y = pep ? YP : YR;

  f32x4 acc[2][4];
  #pragma unroll
  for (int i = 0; i < 2; ++i)
    #pragma unroll
    for (int j = 0; j < 4; ++j) acc[i][j] = (f32x4){0.f, 0.f, 0.f, 0.f};
  agg_core_n64(pb, L, Bb, BL, m0, n0, acc);

  int t = threadIdx.x;
  int wave = t >> 6, lane = t & 63;
  int quad = lane >> 4, l16 = lane & 15;
  int wm = wave * 32;
  int gRow = b * L;
  #pragma unroll
  for (int fi = 0; fi < 2; ++fi)
    #pragma unroll
    for (int r = 0; r < 4; ++r) {
      int m = m0 + wm + fi * 16 + quad * 4 + r;
      int gi = gRow + m;
      float di = dinv[gi];
      float rm = mask ? mask[gi] : 1.f;
      #pragma unroll
      for (int fj = 0; fj < 4; ++fj) {
        int n = n0 + fj * 16 + l16;
        float v = acc[fi][fj][r] * di + bias[n];
        if (encE) v += (float)encE[(size_t)gi * DG + n];
        v = fmaxf(v, 0.f);
        v *= rm;
        Y[(size_t)gi * DG + n] = (__bf16)v;
      }
    }
}

// ---------------------------------------------------------------------------
// fct merged: grid (16, 7, 18). bz<16: pro (b=bz, n0=bx*64 over LR);
// bz>=16: pep (chunk=(bz-16)*16+bx over BLp flattened). out f32.
// ---------------------------------------------------------------------------
__global__ __launch_bounds__(256) void fct_merged(
    const __bf16* __restrict__ WtBp, const float* __restrict__ btp,
    const __bf16* __restrict__ Yp, float* __restrict__ outP,
    const __bf16* __restrict__ WtBr, const float* __restrict__ btr,
    const __bf16* __restrict__ Yr, float* __restrict__ outR) {
  int kh = blockIdx.y;
  int pro = (blockIdx.z < 16);
  const ushort* A;
  const ushort* B;
  const float* bt;
  int n0;
  if (pro) {
    A = (const ushort*)(WtBr + (size_t)kh * DD * DG);
    B = (const ushort*)(Yr + (size_t)blockIdx.z * LR * DG);
    bt = btr;
    n0 = blockIdx.x * 64;
  } else {
    A = (const ushort*)(WtBp + (size_t)kh * DD * DG);
    B = (const ushort*)Yp;
    bt = btp;
    n0 = ((blockIdx.z - 16) * 16 + blockIdx.x) * 64;
  }

  f32x4 acc[2][4];
  #pragma unroll
  for (int i = 0; i < 2; ++i)
    #pragma unroll
    for (int j = 0; j < 4; ++j) acc[i][j] = (f32x4){0.f, 0.f, 0.f, 0.f};
  mfma_core_n64(A, DG, B, DG, 0, n0, 0, DG, acc);

  int t = threadIdx.x;
  int wave = t >> 6, lane = t & 63;
  int quad = lane >> 4, l16 = lane & 15;
  int wm = wave * 32;
  #pragma unroll
  for (int fi = 0; fi < 2; ++fi)
    #pragma unroll
    for (int r = 0; r < 4; ++r) {
      int m = wm + fi * 16 + quad * 4 + r;
      float bb = bt[kh * DD + m];
      #pragma unroll
      for (int fj = 0; fj < 4; ++fj) {
        int n = n0 + fj * 16 + l16;
        float v = fmaxf(acc[fi][fj][r] + bb, 0.f);
        if (pro) {
          outR[((size_t)(kh * BSZ + blockIdx.z) * DD + m) * LR + n] = v;
        } else {
          int b = n >> 7, l = n & 127;
          outP[((size_t)(kh * BSZ + b) * DD + m) * LP + l] = v;
        }
      }
    }
}

// ---------------------------------------------------------------------------
extern "C" void kernel_launch(void* const* d_in, const int* in_sizes, int n_in,
                              void* d_out, int out_size, void* d_ws, size_t ws_size,
                              hipStream_t stream) {
  const int*   x_pep          = (const int*)d_in[0];
  const int*   x_ss_pep       = (const int*)d_in[1];
  const int*   x_2_pep       = (const int*)d_in[2];
  const float* x_dense_pep    = (const float*)d_in[3];
  const float* x_pretrain_pep = (const float*)d_in[4];
  const int*   x_pro          = (const int*)d_in[5];
  const int*   x_ss_pro       = (const int*)d_in[6];
  const int*   x_2_pro        = (const int*)d_in[7];
  const float* x_dense_pro    = (const float*)d_in[8];
  const float* x_pretrain_pro = (const float*)d_in[9];
  const float* x_edge_pep     = (const float*)d_in[10];
  const float* x_edge_pro     = (const float*)d_in[11];
  const float* mask_pep       = (const float*)d_in[12];
  const float* mask_pro       = (const float*)d_in[13];
  const float* E_seq          = (const float*)d_in[14];
  const float* E_ss           = (const float*)d_in[15];
  const float* E_two          = (const float*)d_in[16];
  const float* W_dpep         = (const float*)d_in[17];
  const float* b_dpep         = (const float*)d_in[18];
  const float* W_dpro         = (const float*)d_in[19];
  const float* b_dpro         = (const float*)d_in[20];
  const float* W_ppep         = (const float*)d_in[21];
  const float* b_ppep         = (const float*)d_in[22];
  const float* W_ppro         = (const float*)d_in[23];
  const float* b_ppro         = (const float*)d_in[24];
  const float* Wg_pep1        = (const float*)d_in[25];
  const float* bg_pep1        = (const float*)d_in[26];
  const float* Wg_pep2        = (const float*)d_in[27];
  const float* bg_pep2        = (const float*)d_in[28];
  const float* Wg_pro1        = (const float*)d_in[29];
  const float* bg_pro1        = (const float*)d_in[30];
  const float* Wg_pro2        = (const float*)d_in[31];
  const float* bg_pro2        = (const float*)d_in[32];
  const float* Wt_pep         = (const float*)d_in[33];
  const float* bt_pep         = (const float*)d_in[34];
  const float* Wt_pro         = (const float*)d_in[35];
  const float* bt_pro         = (const float*)d_in[36];

  float* out = (float*)d_out;
  const int BLp = BSZ * LP;   // 2048
  const int BLr = BSZ * LR;   // 16384
  const size_t out_pro_off = (size_t)KH * BSZ * DD * LP;

  // Workspace layout (~117 MB)
  char* w = (char*)d_ws;
  __bf16* encBp  = (__bf16*)w; w += (size_t)BLp * DG * 2;
  __bf16* encBr  = (__bf16*)w; w += (size_t)BLr * DG * 2;
  __bf16* bufATp = (__bf16*)w; w += (size_t)DG * BLp * 2;
  __bf16* bufATr = (__bf16*)w; w += (size_t)DG * BLr * 2;
  __bf16* bufYp  = (__bf16*)w; w += (size_t)BLp * DG * 2;
  __bf16* bufYr  = (__bf16*)w; w += (size_t)BLr * DG * 2;
  __bf16* WppTp  = (__bf16*)w; w += (size_t)DD * 1024 * 2;
  __bf16* WppTr  = (__bf16*)w; w += (size_t)DD * 1024 * 2;
  __bf16* Wg1Tp  = (__bf16*)w; w += (size_t)DG * DG * 2;
  __bf16* Wg2Tp  = (__bf16*)w; w += (size_t)DG * DG * 2;
  __bf16* Wg1Tr  = (__bf16*)w; w += (size_t)DG * DG * 2;
  __bf16* Wg2Tr  = (__bf16*)w; w += (size_t)DG * DG * 2;
  __bf16* WtBp   = (__bf16*)w; w += (size_t)KH * DD * DG * 2;
  __bf16* WtBr   = (__bf16*)w; w += (size_t)KH * DD * DG * 2;
  uint32* packedP = (uint32*)w; w += (size_t)BSZ * (LP / 32) * LP * 4;
  uint32* packedR = (uint32*)w; w += (size_t)BSZ * (LR / 32) * LR * 4;
  float* dinvP = (float*)w; w += (size_t)BLp * 4;
  float* dinvR = (float*)w; w += (size_t)BLr * 4;
  float* partP = (float*)w; w += (size_t)SPLITK * BLp * DD * 4;
  float* partR = (float*)w; w += (size_t)SPLITK * BLr * DD * 4;

  // 1. weights + adjacency pack (single merged dispatch, no atomics)
  prep_all<<<5088, 256, 0, stream>>>(
      W_ppep, W_ppro, Wg_pep1, Wg_pep2, Wg_pro1, Wg_pro2, Wt_pep, Wt_pro,
      x_edge_pep, x_edge_pro,
      WppTp, WppTr, Wg1Tp, Wg2Tp, Wg1Tr, Wg2Tr, WtBp, WtBr,
      packedP, packedR);
  // 2. pretrain split-K partials
  pre_gemm<<<dim3((BLp + BLr) / 64, SPLITK), 256, 0, stream>>>(
      x_pretrain_pep, x_pretrain_pro, WppTp, WppTr, partP, partR);
  // 3. encoder (+ pretrain reduce + dinv from popcount)
  encoder_merged<<<BLp + BLr, 128, 0, stream>>>(
      x_pep, x_ss_pep, x_2_pep, x_dense_pep, W_dpep, b_dpep, mask_pep, partP,
      b_ppep, encBp, packedP, dinvP,
      x_pro, x_ss_pro, x_2_pro, x_dense_pro, W_dpro, b_dpro, mask_pro, partR,
      b_ppro, encBr, packedR, dinvR,
      E_seq, E_ss, E_two);
  // 4-7. GCN
  linT_merged<<<dim3((BLp + BLr) / 64, DG / 128), 256, 0, stream>>>(
      Wg1Tp, encBp, dinvP, bufATp, Wg1Tr, encBr, dinvR, bufATr);
  agg_merged<<<dim3(160, 9), 256, 0, stream>>>(
      packedP, bufATp, dinvP, bg_pep1, nullptr, nullptr, bufYp,
      packedR, bufATr, dinvR, bg_pro1, nullptr, nullptr, bufYr);
  linT_merged<<<dim3((BLp + BLr) / 64, DG / 128), 256, 0, stream>>>(
      Wg2Tp, bufYp, dinvP, bufATp, Wg2Tr, bufYr, dinvR, bufATr);
  agg_merged<<<dim3(160, 9), 256, 0, stream>>>(
      packedP, bufATp, dinvP, bg_pep2, encBp, mask_pep, bufYp,
      packedR, bufATr, dinvR, bg_pro2, encBr, mask_pro, bufYr);
  // 8. fct
  fct_merged<<<dim3(16, KH, 18), 256, 0, stream>>>(
      WtBp, bt_pep, bufYp, out,
      WtBr, bt_pro, bufYr, out + out_pro_off);
}